// Round 1
// baseline (297.703 us; speedup 1.0000x reference)
//
#include <hip/hip_runtime.h>

#define D_MODEL 1024
#define NHEAD 16
#define LN_EPS 1e-5f
#define CHUNK 64
#define S_LEN 4096

typedef unsigned short u16;
typedef __attribute__((ext_vector_type(8))) short short8;
typedef __attribute__((ext_vector_type(4))) float f32x4;

__device__ __forceinline__ u16 f2b(float f) {
  unsigned u = __builtin_bit_cast(unsigned, f);
  u += 0x7FFFu + ((u >> 16) & 1u);   // RNE
  return (u16)(u >> 16);
}
__device__ __forceinline__ float b2f(u16 s) {
  return __builtin_bit_cast(float, ((unsigned)s) << 16);
}

// ---------------- fp32 -> bf16 bulk convert ----------------
__global__ __launch_bounds__(256) void cvt_f32_bf16(const float4* __restrict__ src,
                                                    ushort4* __restrict__ dst, int n4) {
  int i = blockIdx.x * blockDim.x + threadIdx.x;
  int stride = gridDim.x * blockDim.x;
  for (; i < n4; i += stride) {
    float4 f = src[i];
    ushort4 o;
    o.x = f2b(f.x); o.y = f2b(f.y); o.z = f2b(f.z); o.w = f2b(f.w);
    dst[i] = o;
  }
}

__global__ void lam_kernel(const float* __restrict__ beta, float* __restrict__ lam) {
  int h = threadIdx.x;
  if (h < NHEAD) lam[h] = 1.f / (1.f + __expf(-beta[h]));
}

// T2-style XOR swizzle for 128-byte LDS rows (64 bf16 per row)
__device__ __forceinline__ int swz(int byte) {
  return byte ^ (((byte >> 7) & 7) << 4);
}

// Out[M,N] = X[M,K] @ W[N,K]^T   (bf16 inputs, fp32 accumulate)
// 128x128 tile, BK=64, 4 waves (2x2), each wave 64x64 via 4x4 of 16x16x32 MFMA.
template <typename OutT>
__global__ __launch_bounds__(256) void gemm_bt(const u16* __restrict__ X,
                                               const u16* __restrict__ W,
                                               OutT* __restrict__ Out,
                                               int M, int N, int K) {
  __shared__ u16 As[128 * 64];
  __shared__ u16 Bs[128 * 64];
  const int tid = threadIdx.x;
  const int lane = tid & 63;
  const int wave = tid >> 6;
  const int ln15 = lane & 15, lh = lane >> 4;
  const int wr = wave >> 1, wc = wave & 1;
  const int bm = blockIdx.x * 128, bn = blockIdx.y * 128;

  f32x4 acc[4][4];
  f32x4 zero = {0.f, 0.f, 0.f, 0.f};
  #pragma unroll
  for (int m = 0; m < 4; ++m)
    #pragma unroll
    for (int n = 0; n < 4; ++n) acc[m][n] = zero;

  for (int kt = 0; kt < K; kt += 64) {
    __syncthreads();
    #pragma unroll
    for (int i = 0; i < 4; ++i) {
      int ch = tid + 256 * i;          // 16B chunk id, 1024 chunks per tile
      int row = ch >> 3, kc = (ch & 7) << 3;
      uint4 xa = *(const uint4*)(X + (size_t)(bm + row) * K + kt + kc);
      uint4 wa = *(const uint4*)(W + (size_t)(bn + row) * K + kt + kc);
      int sb = swz(ch << 4);
      *(uint4*)((char*)As + sb) = xa;
      *(uint4*)((char*)Bs + sb) = wa;
    }
    __syncthreads();
    #pragma unroll
    for (int ks = 0; ks < 64; ks += 32) {
      short8 a[4], b[4];
      #pragma unroll
      for (int m = 0; m < 4; ++m)
        a[m] = *(const short8*)((const char*)As +
                 swz((wr * 64 + m * 16 + ln15) * 128 + (ks + lh * 8) * 2));
      #pragma unroll
      for (int n = 0; n < 4; ++n)
        b[n] = *(const short8*)((const char*)Bs +
                 swz((wc * 64 + n * 16 + ln15) * 128 + (ks + lh * 8) * 2));
      #pragma unroll
      for (int m = 0; m < 4; ++m)
        #pragma unroll
        for (int n = 0; n < 4; ++n)
          acc[m][n] = __builtin_amdgcn_mfma_f32_16x16x32_bf16(a[m], b[n], acc[m][n], 0, 0, 0);
    }
  }
  #pragma unroll
  for (int m = 0; m < 4; ++m)
    #pragma unroll
    for (int n = 0; n < 4; ++n)
      #pragma unroll
      for (int r = 0; r < 4; ++r) {
        int row = bm + wr * 64 + m * 16 + lh * 4 + r;   // C/D: row=(lane>>4)*4+reg
        int col = bn + wc * 64 + n * 16 + ln15;         //       col=lane&15
        float vv = acc[m][n][r];
        if constexpr (sizeof(OutT) == 2) Out[(size_t)row * N + col] = f2b(vv);
        else                             Out[(size_t)row * N + col] = vv;
      }
}

// ---------------- chunked EMA scan ----------------
// pass 1: per-(b,chunk) local inclusive scan (in place, bf16 storage, fp32 regs)
__global__ __launch_bounds__(256) void scan_local(u16* __restrict__ v,
                                                  float* __restrict__ carry,
                                                  const float* __restrict__ lam,
                                                  int S, int nch) {
  int bj = blockIdx.x;
  int b = bj / nch, j = bj - b * nch;
  int col0 = threadIdx.x * 4;
  float l = lam[col0 >> 6];
  float s0 = 0.f, s1 = 0.f, s2 = 0.f, s3 = 0.f;
  size_t base = ((size_t)b * S + (size_t)j * CHUNK) * D_MODEL + col0;
  for (int t = 0; t < CHUNK; ++t) {
    ushort4* p = (ushort4*)(v + base + (size_t)t * D_MODEL);
    ushort4 u = *p;
    s0 = l * s0 + b2f(u.x);
    s1 = l * s1 + b2f(u.y);
    s2 = l * s2 + b2f(u.z);
    s3 = l * s3 + b2f(u.w);
    u.x = f2b(s0); u.y = f2b(s1); u.z = f2b(s2); u.w = f2b(s3);
    *p = u;
  }
  size_t cb = (size_t)bj * D_MODEL + col0;
  carry[cb] = s0; carry[cb + 1] = s1; carry[cb + 2] = s2; carry[cb + 3] = s3;
}

// pass 2: sequential combine of chunk carries: c_j = lam^C * c_{j-1} + c_j
__global__ void scan_carry(float* __restrict__ carry, const float* __restrict__ lam,
                           int B, int nch) {
  int idx = blockIdx.x * blockDim.x + threadIdx.x;
  if (idx >= B * D_MODEL) return;
  int b = idx >> 10, col = idx & (D_MODEL - 1);
  float l = lam[col >> 6];
  float lC = __powf(l, (float)CHUNK);
  float c = 0.f;
  for (int j = 0; j < nch; ++j) {
    size_t a = ((size_t)(b * nch + j)) * D_MODEL + col;
    c = lC * c + carry[a];
    carry[a] = c;
  }
}

// pass 3 fused with q*state, LayerNorm, SiLU gate. One block per row.
__global__ __launch_bounds__(256) void ew_ln(const u16* __restrict__ qb,
    const u16* __restrict__ stb, const float* __restrict__ carry,
    const u16* __restrict__ gpre, const float* __restrict__ lam,
    const float* __restrict__ gamma, const float* __restrict__ lbeta,
    u16* __restrict__ yout, int S, int nch) {
  int row = blockIdx.x;
  int b = row / S, s = row - b * S;
  int j = s / CHUNK, tl = s - j * CHUNK;
  int tid = threadIdx.x;
  int col0 = tid * 4;
  size_t rb = (size_t)row * D_MODEL;

  ushort4 qu = *(const ushort4*)(qb + rb + col0);
  ushort4 su = *(const ushort4*)(stb + rb + col0);
  float st[4] = {b2f(su.x), b2f(su.y), b2f(su.z), b2f(su.w)};
  if (j > 0) {
    float l = lam[col0 >> 6];
    float p = __powf(l, (float)(tl + 1));
    const float4 c4 = *(const float4*)(carry + ((size_t)(b * nch + j - 1)) * D_MODEL + col0);
    st[0] += p * c4.x; st[1] += p * c4.y; st[2] += p * c4.z; st[3] += p * c4.w;
  }
  float q[4] = {b2f(qu.x), b2f(qu.y), b2f(qu.z), b2f(qu.w)};
  float y[4];
  float sum = 0.f, sumsq = 0.f;
  #pragma unroll
  for (int i = 0; i < 4; ++i) {
    y[i] = q[i] * st[i];
    sum += y[i];
    sumsq += y[i] * y[i];
  }
  #pragma unroll
  for (int off = 32; off > 0; off >>= 1) {
    sum += __shfl_down(sum, off);
    sumsq += __shfl_down(sumsq, off);
  }
  __shared__ float red[8];
  int ln = tid & 63, wv = tid >> 6;
  if (ln == 0) { red[wv] = sum; red[4 + wv] = sumsq; }
  __syncthreads();
  sum = red[0] + red[1] + red[2] + red[3];
  sumsq = red[4] + red[5] + red[6] + red[7];
  float mu = sum * (1.f / 1024.f);
  float var = sumsq * (1.f / 1024.f) - mu * mu;
  float rstd = rsqrtf(var + LN_EPS);

  float4 gm = *(const float4*)(gamma + col0);
  float4 bt = *(const float4*)(lbeta + col0);
  ushort4 gu = *(const ushort4*)(gpre + rb + col0);
  float gv[4]  = {b2f(gu.x), b2f(gu.y), b2f(gu.z), b2f(gu.w)};
  float gmv[4] = {gm.x, gm.y, gm.z, gm.w};
  float btv[4] = {bt.x, bt.y, bt.z, bt.w};
  u16 ov[4];
  #pragma unroll
  for (int i = 0; i < 4; ++i) {
    float gate = gv[i] / (1.f + __expf(-gv[i]));   // SiLU
    float oo = ((y[i] - mu) * rstd * gmv[i] + btv[i]) * gate;
    ov[i] = f2b(oo);
  }
  ushort4 o; o.x = ov[0]; o.y = ov[1]; o.z = ov[2]; o.w = ov[3];
  *(ushort4*)(yout + rb + col0) = o;
}

extern "C" void kernel_launch(void* const* d_in, const int* in_sizes, int n_in,
                              void* d_out, int out_size, void* d_ws, size_t ws_size,
                              hipStream_t stream) {
  const float* x     = (const float*)d_in[0];
  const float* Wq    = (const float*)d_in[1];
  const float* Wv    = (const float*)d_in[2];
  const float* Wo    = (const float*)d_in[3];
  const float* Wg    = (const float*)d_in[4];
  const float* beta  = (const float*)d_in[5];
  const float* gamma = (const float*)d_in[6];
  const float* lbeta = (const float*)d_in[7];
  float* out = (float*)d_out;

  const int BS = in_sizes[0] / D_MODEL;     // 16384
  const int S = S_LEN;                       // 4096
  const int B = BS / S;                      // 4
  const int nch = S / CHUNK;                 // 64
  const size_t nx = (size_t)BS * D_MODEL;
  const size_t nw = (size_t)D_MODEL * D_MODEL;

  char* w = (char*)d_ws;
  u16* xb  = (u16*)w;  w += nx * 2;
  u16* wqb = (u16*)w;  w += nw * 2;
  u16* wvb = (u16*)w;  w += nw * 2;
  u16* wgb = (u16*)w;  w += nw * 2;
  u16* wob = (u16*)w;  w += nw * 2;
  u16* qb  = (u16*)w;  w += nx * 2;
  u16* vb  = (u16*)w;  w += nx * 2;
  u16* yb  = (u16*)w;  w += nx * 2;
  float* carry = (float*)w;  w += (size_t)B * nch * D_MODEL * 4;
  float* lam = (float*)w;

  cvt_f32_bf16<<<2048, 256, 0, stream>>>((const float4*)x,  (ushort4*)xb,  (int)(nx / 4));
  cvt_f32_bf16<<<1024, 256, 0, stream>>>((const float4*)Wq, (ushort4*)wqb, (int)(nw / 4));
  cvt_f32_bf16<<<1024, 256, 0, stream>>>((const float4*)Wv, (ushort4*)wvb, (int)(nw / 4));
  cvt_f32_bf16<<<1024, 256, 0, stream>>>((const float4*)Wg, (ushort4*)wgb, (int)(nw / 4));
  cvt_f32_bf16<<<1024, 256, 0, stream>>>((const float4*)Wo, (ushort4*)wob, (int)(nw / 4));
  lam_kernel<<<1, 64, 0, stream>>>(beta, lam);

  dim3 gg(BS / 128, D_MODEL / 128);
  u16* gb = (u16*)d_out;   // stash g_pre (bf16) in d_out; overwritten by final GEMM
  gemm_bt<u16><<<gg, 256, 0, stream>>>(xb, wqb, qb, BS, D_MODEL, D_MODEL);
  gemm_bt<u16><<<gg, 256, 0, stream>>>(xb, wvb, vb, BS, D_MODEL, D_MODEL);
  gemm_bt<u16><<<gg, 256, 0, stream>>>(xb, wgb, gb, BS, D_MODEL, D_MODEL);

  scan_local<<<B * nch, 256, 0, stream>>>(vb, carry, lam, S, nch);
  scan_carry<<<(B * D_MODEL + 255) / 256, 256, 0, stream>>>(carry, lam, B, nch);
  ew_ln<<<BS, 256, 0, stream>>>(qb, vb, carry, gb, lam, gamma, lbeta, yb, S, nch);
  gemm_bt<float><<<gg, 256, 0, stream>>>(yb, wob, out, BS, D_MODEL, D_MODEL);
}

// Round 2
// 276.573 us; speedup vs baseline: 1.0764x; 1.0764x over previous
//
#include <hip/hip_runtime.h>

#define D_MODEL 1024
#define NHEAD 16
#define LN_EPS 1e-5f
#define CHUNK 64
#define S_LEN 4096

typedef unsigned short u16;
typedef __attribute__((ext_vector_type(8))) short short8;
typedef __attribute__((ext_vector_type(4))) float f32x4;

__device__ __forceinline__ u16 f2b(float f) {
  unsigned u = __builtin_bit_cast(unsigned, f);
  u += 0x7FFFu + ((u >> 16) & 1u);   // RNE
  return (u16)(u >> 16);
}
__device__ __forceinline__ float b2f(u16 s) {
  return __builtin_bit_cast(float, ((unsigned)s) << 16);
}

// ---------------- fp32 -> bf16 bulk convert ----------------
__global__ __launch_bounds__(256) void cvt_f32_bf16(const float4* __restrict__ src,
                                                    ushort4* __restrict__ dst, int n4) {
  int i = blockIdx.x * blockDim.x + threadIdx.x;
  int stride = gridDim.x * blockDim.x;
  for (; i < n4; i += stride) {
    float4 f = src[i];
    ushort4 o;
    o.x = f2b(f.x); o.y = f2b(f.y); o.z = f2b(f.z); o.w = f2b(f.w);
    dst[i] = o;
  }
}

__global__ void lam_kernel(const float* __restrict__ beta, float* __restrict__ lam) {
  int h = threadIdx.x;
  if (h < NHEAD) lam[h] = 1.f / (1.f + __expf(-beta[h]));
}

// ================= 256x256 tile, BK=32, 3-deep pipelined GEMM =================
// Out[M,N] = X[M,K] @ W[N,K]^T  (bf16 in, fp32 accum). 512 thr = 8 waves (2Mx4N),
// per-wave output 128x64 (8x4 frags of 16x16). LDS: 3 bufs x {A,B} x 256x32 bf16
// = 96 KiB -> 1 block/CU, 2 waves/SIMD. Staging via global_load_lds width-16,
// linear LDS (64B rows => frag ds_read_b128 covers contiguous 1KiB: conflict-free).
// Counted vmcnt(4) at tile boundary keeps next-next tile's loads in flight (T3+T4);
// setprio around MFMA clusters (T5).

#define SLOT (256 * 32)

__device__ __forceinline__ void glds16(const u16* g, const u16* l) {
  __builtin_amdgcn_global_load_lds(
      (const __attribute__((address_space(1))) unsigned*)g,
      (__attribute__((address_space(3))) unsigned*)l, 16, 0, 0);
}

template <typename OutT>
__global__ __launch_bounds__(512, 2) void gemm256(const u16* __restrict__ X,
                                                  const u16* __restrict__ W,
                                                  OutT* __restrict__ Out,
                                                  int M, int N, int K) {
  __shared__ u16 sm[3][2][SLOT];
  const int tid = threadIdx.x;
  const int lane = tid & 63;
  const int wave = tid >> 6;              // 0..7
  const int ln15 = lane & 15, lh = lane >> 4;
  const int wr = wave >> 2, wc = wave & 3;
  const int bm = blockIdx.x * 256, bn = blockIdx.y * 256;
  const int NT = K >> 5;                  // K-tiles of 32

  const int lrow = lane >> 2;             // 0..15 (row within 16-row stripe)
  const int lcol = (lane & 3) << 3;       // u16 col within 32-col row

  // per-lane global bases for this wave's staging stripes (A rows / W rows)
  const u16* Ag = X + (size_t)(bm + wave * 32 + lrow) * K + lcol;
  const u16* Bg = W + (size_t)(bn + wave * 32 + lrow) * K + lcol;
  const int lw = wave * 1024;             // wave's LDS stripe base (elems), uniform

  const int aoff = (wr * 128 + ln15) * 32 + lh * 8;   // frag read base, A
  const int boff = (wc * 64 + ln15) * 32 + lh * 8;    // frag read base, B

  f32x4 acc[8][4];
  f32x4 zero = {0.f, 0.f, 0.f, 0.f};
  #pragma unroll
  for (int m = 0; m < 8; ++m)
    #pragma unroll
    for (int n = 0; n < 4; ++n) acc[m][n] = zero;

  // ---- prologue: stage tiles 0 and 1 (4 loads each per wave) ----
  #pragma unroll
  for (int tt = 0; tt < 2; ++tt) {
    const u16* Agt = Ag + tt * 32;
    const u16* Bgt = Bg + tt * 32;
    glds16(Agt,          sm[tt][0] + lw);
    glds16(Agt + 16 * K, sm[tt][0] + lw + 512);
    glds16(Bgt,          sm[tt][1] + lw);
    glds16(Bgt + 16 * K, sm[tt][1] + lw + 512);
  }
  asm volatile("s_waitcnt vmcnt(4)" ::: "memory");   // tile 0 landed
  asm volatile("s_barrier" ::: "memory");

  for (int t = 0; t < NT; ++t) {
    const int cur = t % 3;
    const int nb = (t + 2) % 3;
    const int t2 = t + 2;
    const bool st = (t2 < NT);
    const u16* fA = sm[cur][0] + aoff;
    const u16* fB = sm[cur][1] + boff;
    const u16* Agt = Ag + t2 * 32;
    const u16* Bgt = Bg + t2 * 32;

    short8 a[8], b[4];
    // ---- phase 0: read a0..3, b0..1; stage A half 0 ----
    #pragma unroll
    for (int m = 0; m < 4; ++m) a[m] = *(const short8*)(fA + m * 512);
    b[0] = *(const short8*)(fB);
    b[1] = *(const short8*)(fB + 512);
    if (st) glds16(Agt, sm[nb][0] + lw);
    asm volatile("s_barrier" ::: "memory");
    __builtin_amdgcn_sched_barrier(0);
    __builtin_amdgcn_s_setprio(1);
    #pragma unroll
    for (int m = 0; m < 4; ++m)
      #pragma unroll
      for (int n = 0; n < 2; ++n)
        acc[m][n] = __builtin_amdgcn_mfma_f32_16x16x32_bf16(a[m], b[n], acc[m][n], 0, 0, 0);
    __builtin_amdgcn_s_setprio(0);
    __builtin_amdgcn_sched_barrier(0);
    asm volatile("s_barrier" ::: "memory");

    // ---- phase 1: read a4..7, b2..3; stage A half 1 ----
    #pragma unroll
    for (int m = 4; m < 8; ++m) a[m] = *(const short8*)(fA + m * 512);
    b[2] = *(const short8*)(fB + 2 * 512);
    b[3] = *(const short8*)(fB + 3 * 512);
    if (st) glds16(Agt + 16 * K, sm[nb][0] + lw + 512);
    asm volatile("s_barrier" ::: "memory");
    __builtin_amdgcn_sched_barrier(0);
    __builtin_amdgcn_s_setprio(1);
    #pragma unroll
    for (int m = 4; m < 8; ++m)
      #pragma unroll
      for (int n = 0; n < 2; ++n)
        acc[m][n] = __builtin_amdgcn_mfma_f32_16x16x32_bf16(a[m], b[n], acc[m][n], 0, 0, 0);
    __builtin_amdgcn_s_setprio(0);
    __builtin_amdgcn_sched_barrier(0);
    asm volatile("s_barrier" ::: "memory");

    // ---- phase 2: stage B half 0 ----
    if (st) glds16(Bgt, sm[nb][1] + lw);
    __builtin_amdgcn_sched_barrier(0);
    __builtin_amdgcn_s_setprio(1);
    #pragma unroll
    for (int m = 0; m < 4; ++m)
      #pragma unroll
      for (int n = 2; n < 4; ++n)
        acc[m][n] = __builtin_amdgcn_mfma_f32_16x16x32_bf16(a[m], b[n], acc[m][n], 0, 0, 0);
    __builtin_amdgcn_s_setprio(0);
    __builtin_amdgcn_sched_barrier(0);
    asm volatile("s_barrier" ::: "memory");

    // ---- phase 3: stage B half 1; tile-boundary counted wait ----
    if (st) glds16(Bgt + 16 * K, sm[nb][1] + lw + 512);
    __builtin_amdgcn_sched_barrier(0);
    __builtin_amdgcn_s_setprio(1);
    #pragma unroll
    for (int m = 4; m < 8; ++m)
      #pragma unroll
      for (int n = 2; n < 4; ++n)
        acc[m][n] = __builtin_amdgcn_mfma_f32_16x16x32_bf16(a[m], b[n], acc[m][n], 0, 0, 0);
    __builtin_amdgcn_s_setprio(0);
    __builtin_amdgcn_sched_barrier(0);
    if (t < NT - 2) {
      asm volatile("s_waitcnt vmcnt(4)" ::: "memory");   // tile t+1 landed, t+2 in flight
    } else if (t == NT - 2) {
      asm volatile("s_waitcnt vmcnt(0)" ::: "memory");   // drain before last tile
    }
    asm volatile("s_barrier" ::: "memory");
  }

  // ---- epilogue: C write ----
  #pragma unroll
  for (int m = 0; m < 8; ++m)
    #pragma unroll
    for (int n = 0; n < 4; ++n)
      #pragma unroll
      for (int r = 0; r < 4; ++r) {
        int row = bm + wr * 128 + m * 16 + lh * 4 + r;   // C/D: row=(lane>>4)*4+reg
        int col = bn + wc * 64 + n * 16 + ln15;          //      col=lane&15
        float vv = acc[m][n][r];
        if constexpr (sizeof(OutT) == 2) Out[(size_t)row * N + col] = f2b(vv);
        else                             Out[(size_t)row * N + col] = vv;
      }
}

// ---------------- chunked EMA scan (packed qvg layout, ld = 3072) ----------------
__global__ __launch_bounds__(256) void scan_local(u16* __restrict__ v,
                                                  float* __restrict__ carry,
                                                  const float* __restrict__ lam,
                                                  int S, int nch, int ld) {
  int bj = blockIdx.x;
  int b = bj / nch, j = bj - b * nch;
  int col0 = threadIdx.x * 4;
  float l = lam[col0 >> 6];
  float s0 = 0.f, s1 = 0.f, s2 = 0.f, s3 = 0.f;
  size_t base = ((size_t)b * S + (size_t)j * CHUNK) * ld + col0;
  for (int t = 0; t < CHUNK; ++t) {
    ushort4* p = (ushort4*)(v + base + (size_t)t * ld);
    ushort4 u = *p;
    s0 = l * s0 + b2f(u.x);
    s1 = l * s1 + b2f(u.y);
    s2 = l * s2 + b2f(u.z);
    s3 = l * s3 + b2f(u.w);
    u.x = f2b(s0); u.y = f2b(s1); u.z = f2b(s2); u.w = f2b(s3);
    *p = u;
  }
  size_t cb = (size_t)bj * D_MODEL + col0;
  carry[cb] = s0; carry[cb + 1] = s1; carry[cb + 2] = s2; carry[cb + 3] = s3;
}

__global__ void scan_carry(float* __restrict__ carry, const float* __restrict__ lam,
                           int B, int nch) {
  int idx = blockIdx.x * blockDim.x + threadIdx.x;
  if (idx >= B * D_MODEL) return;
  int b = idx >> 10, col = idx & (D_MODEL - 1);
  float l = lam[col >> 6];
  float lC = __powf(l, (float)CHUNK);
  float c = 0.f;
  for (int j = 0; j < nch; ++j) {
    size_t a = ((size_t)(b * nch + j)) * D_MODEL + col;
    c = lC * c + carry[a];
    carry[a] = c;
  }
}

// pass 3 fused with q*state, LayerNorm, SiLU gate. One block per row.
__global__ __launch_bounds__(256) void ew_ln(const u16* __restrict__ qvg,
    const float* __restrict__ carry, const float* __restrict__ lam,
    const float* __restrict__ gamma, const float* __restrict__ lbeta,
    u16* __restrict__ yout, int S, int nch, int ld) {
  int row = blockIdx.x;
  int b = row / S, s = row - b * S;
  int j = s / CHUNK, tl = s - j * CHUNK;
  int tid = threadIdx.x;
  int col0 = tid * 4;
  size_t rb = (size_t)row * ld;

  ushort4 qu = *(const ushort4*)(qvg + rb + col0);
  ushort4 su = *(const ushort4*)(qvg + rb + D_MODEL + col0);
  float st[4] = {b2f(su.x), b2f(su.y), b2f(su.z), b2f(su.w)};
  if (j > 0) {
    float l = lam[col0 >> 6];
    float p = __powf(l, (float)(tl + 1));
    const float4 c4 = *(const float4*)(carry + ((size_t)(b * nch + j - 1)) * D_MODEL + col0);
    st[0] += p * c4.x; st[1] += p * c4.y; st[2] += p * c4.z; st[3] += p * c4.w;
  }
  float q[4] = {b2f(qu.x), b2f(qu.y), b2f(qu.z), b2f(qu.w)};
  float y[4];
  float sum = 0.f, sumsq = 0.f;
  #pragma unroll
  for (int i = 0; i < 4; ++i) {
    y[i] = q[i] * st[i];
    sum += y[i];
    sumsq += y[i] * y[i];
  }
  #pragma unroll
  for (int off = 32; off > 0; off >>= 1) {
    sum += __shfl_down(sum, off);
    sumsq += __shfl_down(sumsq, off);
  }
  __shared__ float red[8];
  int ln = tid & 63, wv = tid >> 6;
  if (ln == 0) { red[wv] = sum; red[4 + wv] = sumsq; }
  __syncthreads();
  sum = red[0] + red[1] + red[2] + red[3];
  sumsq = red[4] + red[5] + red[6] + red[7];
  float mu = sum * (1.f / 1024.f);
  float var = sumsq * (1.f / 1024.f) - mu * mu;
  float rstd = rsqrtf(var + LN_EPS);

  float4 gm = *(const float4*)(gamma + col0);
  float4 bt = *(const float4*)(lbeta + col0);
  ushort4 gu = *(const ushort4*)(qvg + rb + 2 * D_MODEL + col0);
  float gv[4]  = {b2f(gu.x), b2f(gu.y), b2f(gu.z), b2f(gu.w)};
  float gmv[4] = {gm.x, gm.y, gm.z, gm.w};
  float btv[4] = {bt.x, bt.y, bt.z, bt.w};
  u16 ov[4];
  #pragma unroll
  for (int i = 0; i < 4; ++i) {
    float gate = gv[i] / (1.f + __expf(-gv[i]));   // SiLU
    float oo = ((y[i] - mu) * rstd * gmv[i] + btv[i]) * gate;
    ov[i] = f2b(oo);
  }
  ushort4 o; o.x = ov[0]; o.y = ov[1]; o.z = ov[2]; o.w = ov[3];
  *(ushort4*)(yout + (size_t)row * D_MODEL + col0) = o;
}

extern "C" void kernel_launch(void* const* d_in, const int* in_sizes, int n_in,
                              void* d_out, int out_size, void* d_ws, size_t ws_size,
                              hipStream_t stream) {
  const float* x     = (const float*)d_in[0];
  const float* Wq    = (const float*)d_in[1];
  const float* Wv    = (const float*)d_in[2];
  const float* Wo    = (const float*)d_in[3];
  const float* Wg    = (const float*)d_in[4];
  const float* beta  = (const float*)d_in[5];
  const float* gamma = (const float*)d_in[6];
  const float* lbeta = (const float*)d_in[7];
  float* out = (float*)d_out;

  const int BS = in_sizes[0] / D_MODEL;     // 16384
  const int S = S_LEN;                       // 4096
  const int B = BS / S;                      // 4
  const int nch = S / CHUNK;                 // 64
  const size_t nx = (size_t)BS * D_MODEL;
  const size_t nw = (size_t)D_MODEL * D_MODEL;
  const int N3 = 3 * D_MODEL;                // 3072

  char* w = (char*)d_ws;
  u16* xb   = (u16*)w;  w += nx * 2;
  u16* wqvg = (u16*)w;  w += 3 * nw * 2;     // packed [Wq;Wv;Wg] rows
  u16* wob  = (u16*)w;  w += nw * 2;
  u16* qvg  = (u16*)w;  w += (size_t)BS * N3 * 2;   // packed [q|state|g] per row
  u16* yb   = (u16*)w;  w += nx * 2;
  float* carry = (float*)w;  w += (size_t)B * nch * D_MODEL * 4;
  float* lam = (float*)w;

  cvt_f32_bf16<<<2048, 256, 0, stream>>>((const float4*)x,  (ushort4*)xb, (int)(nx / 4));
  cvt_f32_bf16<<<1024, 256, 0, stream>>>((const float4*)Wq, (ushort4*)(wqvg), (int)(nw / 4));
  cvt_f32_bf16<<<1024, 256, 0, stream>>>((const float4*)Wv, (ushort4*)(wqvg + nw), (int)(nw / 4));
  cvt_f32_bf16<<<1024, 256, 0, stream>>>((const float4*)Wg, (ushort4*)(wqvg + 2 * nw), (int)(nw / 4));
  cvt_f32_bf16<<<1024, 256, 0, stream>>>((const float4*)Wo, (ushort4*)wob, (int)(nw / 4));
  lam_kernel<<<1, 64, 0, stream>>>(beta, lam);

  dim3 g1(BS / 256, N3 / 256);      // 64 x 12
  gemm256<u16><<<g1, 512, 0, stream>>>(xb, wqvg, qvg, BS, N3, D_MODEL);

  scan_local<<<B * nch, 256, 0, stream>>>(qvg + D_MODEL, carry, lam, S, nch, N3);
  scan_carry<<<(B * D_MODEL + 255) / 256, 256, 0, stream>>>(carry, lam, B, nch);
  ew_ln<<<BS, 256, 0, stream>>>(qvg, carry, lam, gamma, lbeta, yb, S, nch, N3);

  dim3 g2(BS / 256, D_MODEL / 256); // 64 x 4
  gemm256<float><<<g2, 512, 0, stream>>>(yb, wob, out, BS, D_MODEL, D_MODEL);
}

// Round 3
// 259.227 us; speedup vs baseline: 1.1484x; 1.0669x over previous
//
#include <hip/hip_runtime.h>

#define D_MODEL 1024
#define NHEAD 16
#define LN_EPS 1e-5f
#define CHUNK 64
#define S_LEN 4096

typedef unsigned short u16;
typedef __attribute__((ext_vector_type(8))) short short8;
typedef __attribute__((ext_vector_type(4))) float f32x4;

__device__ __forceinline__ u16 f2b(float f) {
  unsigned u = __builtin_bit_cast(unsigned, f);
  u += 0x7FFFu + ((u >> 16) & 1u);   // RNE
  return (u16)(u >> 16);
}
__device__ __forceinline__ float b2f(u16 s) {
  return __builtin_bit_cast(float, ((unsigned)s) << 16);
}

// ---------------- fp32 -> bf16 bulk convert ----------------
__global__ __launch_bounds__(256) void cvt_f32_bf16(const float4* __restrict__ src,
                                                    ushort4* __restrict__ dst, int n4) {
  int i = blockIdx.x * blockDim.x + threadIdx.x;
  int stride = gridDim.x * blockDim.x;
  for (; i < n4; i += stride) {
    float4 f = src[i];
    ushort4 o;
    o.x = f2b(f.x); o.y = f2b(f.y); o.z = f2b(f.z); o.w = f2b(f.w);
    dst[i] = o;
  }
}

__global__ void lam_kernel(const float* __restrict__ beta, float* __restrict__ lam) {
  int h = threadIdx.x;
  if (h < NHEAD) lam[h] = 1.f / (1.f + __expf(-beta[h]));
}

// ============ 256x256 tile, BK=64, 2-dbuf 4-phase pipelined GEMM ============
// Out[M,N] = X[M,K] @ W[N,K]^T (bf16 in, fp32 accum). 512 thr = 8 waves (2Mx4N),
// per-wave output 128x64. LDS: 8 units of 16KB = [dbuf][A/B][half][128x64 u16]
// = 128 KiB. Swizzle: 16B chunk c within each 128B row stored at c^(row&7);
// applied by pre-swizzling the GLOBAL source column (glds dest stays linear,
// lane-contiguous) and XOR-ing the ds_read address. Fixed (m,ks) frag read:
// 16 lanes -> bank-quads (ks*4+lh)^(r&7) = 2-way = free.
// Stage stagger: ph1/ph2 of tile t stage B0/B1(t+1) into other dbuf (its B was
// last read at ph3(t-1)); ph3/ph4 stage A0/A1(t+2) into current dbuf (A-halves
// fully ds_read by end of ph2). vmcnt(4) at tile end => tile t+1 fully landed
// while A(t+2)'s 4 loads stay in flight. 16 MFMA per phase under setprio(1).

__device__ __forceinline__ void glds16(const u16* g, const u16* l) {
  __builtin_amdgcn_global_load_lds(
      (const __attribute__((address_space(1))) unsigned*)g,
      (__attribute__((address_space(3))) unsigned*)l, 16, 0, 0);
}

#define BAR() asm volatile("s_barrier" ::: "memory")

template <typename OutT>
__global__ __launch_bounds__(512, 2) void gemm256(const u16* __restrict__ X,
                                                  const u16* __restrict__ W,
                                                  OutT* __restrict__ Out,
                                                  int M, int N, int K) {
  __shared__ u16 sm[8][8192];   // unit = d*4 + ab*2 + h ; 16 KB each
  const int tid = threadIdx.x;
  const int lane = tid & 63;
  const int wave = tid >> 6;              // 0..7
  const int ln15 = lane & 15, lh = lane >> 4;
  const int wr = wave >> 2, wc = wave & 3;
  const int bm = blockIdx.x * 256, bn = blockIdx.y * 256;
  const int NT = K >> 6;                  // K-tiles of 64

  // ---- staging source (pre-swizzled global 16B-chunk within 128B row) ----
  const int srow = tid >> 3;                              // 0..63
  const int scol = ((tid & 7) ^ (srow & 7)) << 3;         // u16 col
  const u16* Asrc = X + (size_t)(bm + srow) * K + scol;
  const u16* Bsrc = W + (size_t)(bn + srow) * K + scol;
  const int ldsw = wave * 512;            // wave's u16 offset inside a unit

#define STAGE(u, h, tile, src)                                          \
  { const u16* _g = (src) + (size_t)((h) * 128) * K + (tile) * 64;      \
    glds16(_g,                 &sm[u][ldsw]);                           \
    glds16(_g + (size_t)64 * K, &sm[u][ldsw + 4096]); }

  // ---- ds_read bases (swizzled) ----
  const char* smb = (const char*)&sm[0][0];
  const char* Ard = smb + wr * 16384 + ln15 * 128;
  const char* Brd = smb + (2 + (wc >> 1)) * 16384 + ((wc & 1) * 64 + ln15) * 128;
  const int swz0 = ((lh ^ (ln15 & 7)) << 4);              // ks=0 chunk
  const int swz1 = (((4 + lh) ^ (ln15 & 7)) << 4);        // ks=1 chunk

  f32x4 acc[8][4];
  f32x4 zero = {0.f, 0.f, 0.f, 0.f};
  #pragma unroll
  for (int m = 0; m < 8; ++m)
    #pragma unroll
    for (int n = 0; n < 4; ++n) acc[m][n] = zero;

  // ---- prologue: tile0 {A0,A1,B0,B1} + tile1 {A0,A1} ----
  STAGE(0, 0, 0, Asrc); STAGE(1, 1, 0, Asrc);
  STAGE(2, 0, 0, Bsrc); STAGE(3, 1, 0, Bsrc);
  STAGE(4, 0, 1, Asrc); STAGE(5, 1, 1, Asrc);
  asm volatile("s_waitcnt vmcnt(4)" ::: "memory");   // tile0 landed; A(1) flying
  BAR();

  for (int t = 0; t < NT; ++t) {
    const int d = t & 1;
    const int db = d * 65536;            // read byte offset for this dbuf
    const int od = (d ^ 1) * 4;          // other dbuf unit base
    const int sd = d * 4;                // same dbuf unit base
    short8 a[8][2], b[4][2];

    // ======== phase 1: read a0-3(ks01)+b0-1(ks01); stage B0(t+1) ========
    #pragma unroll
    for (int m = 0; m < 4; ++m) {
      a[m][0] = *(const short8*)(Ard + db + m * 2048 + swz0);
      a[m][1] = *(const short8*)(Ard + db + m * 2048 + swz1);
    }
    #pragma unroll
    for (int n = 0; n < 2; ++n) {
      b[n][0] = *(const short8*)(Brd + db + n * 2048 + swz0);
      b[n][1] = *(const short8*)(Brd + db + n * 2048 + swz1);
    }
    if (t + 1 < NT) STAGE(od + 2, 0, t + 1, Bsrc);
    BAR();
    asm volatile("s_waitcnt lgkmcnt(0)" ::: "memory");
    __builtin_amdgcn_sched_barrier(0);
    __builtin_amdgcn_s_setprio(1);
    #pragma unroll
    for (int m = 0; m < 4; ++m)
      #pragma unroll
      for (int n = 0; n < 2; ++n) {
        acc[m][n] = __builtin_amdgcn_mfma_f32_16x16x32_bf16(a[m][0], b[n][0], acc[m][n], 0, 0, 0);
        acc[m][n] = __builtin_amdgcn_mfma_f32_16x16x32_bf16(a[m][1], b[n][1], acc[m][n], 0, 0, 0);
      }
    __builtin_amdgcn_s_setprio(0);
    __builtin_amdgcn_sched_barrier(0);
    BAR();

    // ======== phase 2: read a4-7(ks01); stage B1(t+1) ========
    #pragma unroll
    for (int m = 4; m < 8; ++m) {
      a[m][0] = *(const short8*)(Ard + db + m * 2048 + swz0);
      a[m][1] = *(const short8*)(Ard + db + m * 2048 + swz1);
    }
    if (t + 1 < NT) STAGE(od + 3, 1, t + 1, Bsrc);
    BAR();
    asm volatile("s_waitcnt lgkmcnt(0)" ::: "memory");
    __builtin_amdgcn_sched_barrier(0);
    __builtin_amdgcn_s_setprio(1);
    #pragma unroll
    for (int m = 4; m < 8; ++m)
      #pragma unroll
      for (int n = 0; n < 2; ++n) {
        acc[m][n] = __builtin_amdgcn_mfma_f32_16x16x32_bf16(a[m][0], b[n][0], acc[m][n], 0, 0, 0);
        acc[m][n] = __builtin_amdgcn_mfma_f32_16x16x32_bf16(a[m][1], b[n][1], acc[m][n], 0, 0, 0);
      }
    __builtin_amdgcn_s_setprio(0);
    __builtin_amdgcn_sched_barrier(0);
    BAR();

    // ======== phase 3: read b2-3(ks01); stage A0(t+2) ========
    #pragma unroll
    for (int n = 2; n < 4; ++n) {
      b[n][0] = *(const short8*)(Brd + db + n * 2048 + swz0);
      b[n][1] = *(const short8*)(Brd + db + n * 2048 + swz1);
    }
    if (t + 2 < NT) STAGE(sd + 0, 0, t + 2, Asrc);
    BAR();
    asm volatile("s_waitcnt lgkmcnt(0)" ::: "memory");
    __builtin_amdgcn_sched_barrier(0);
    __builtin_amdgcn_s_setprio(1);
    #pragma unroll
    for (int m = 0; m < 4; ++m)
      #pragma unroll
      for (int n = 2; n < 4; ++n) {
        acc[m][n] = __builtin_amdgcn_mfma_f32_16x16x32_bf16(a[m][0], b[n][0], acc[m][n], 0, 0, 0);
        acc[m][n] = __builtin_amdgcn_mfma_f32_16x16x32_bf16(a[m][1], b[n][1], acc[m][n], 0, 0, 0);
      }
    __builtin_amdgcn_s_setprio(0);
    __builtin_amdgcn_sched_barrier(0);
    BAR();

    // ======== phase 4: stage A1(t+2); tile-boundary counted wait ========
    if (t + 2 < NT) STAGE(sd + 1, 1, t + 2, Asrc);
    __builtin_amdgcn_sched_barrier(0);
    __builtin_amdgcn_s_setprio(1);
    #pragma unroll
    for (int m = 4; m < 8; ++m)
      #pragma unroll
      for (int n = 2; n < 4; ++n) {
        acc[m][n] = __builtin_amdgcn_mfma_f32_16x16x32_bf16(a[m][0], b[n][0], acc[m][n], 0, 0, 0);
        acc[m][n] = __builtin_amdgcn_mfma_f32_16x16x32_bf16(a[m][1], b[n][1], acc[m][n], 0, 0, 0);
      }
    __builtin_amdgcn_s_setprio(0);
    __builtin_amdgcn_sched_barrier(0);
    if (t + 2 < NT) {
      asm volatile("s_waitcnt vmcnt(4)" ::: "memory");  // t+1 landed; A(t+2) flying
    } else if (t + 1 < NT) {
      asm volatile("s_waitcnt vmcnt(0)" ::: "memory");  // drain before last tile
    }
    BAR();
  }
#undef STAGE

  // ---- epilogue: C write ----
  #pragma unroll
  for (int m = 0; m < 8; ++m)
    #pragma unroll
    for (int n = 0; n < 4; ++n)
      #pragma unroll
      for (int r = 0; r < 4; ++r) {
        int row = bm + wr * 128 + m * 16 + lh * 4 + r;   // C/D: row=(lane>>4)*4+reg
        int col = bn + wc * 64 + n * 16 + ln15;          //      col=lane&15
        float vv = acc[m][n][r];
        if constexpr (sizeof(OutT) == 2) Out[(size_t)row * N + col] = f2b(vv);
        else                             Out[(size_t)row * N + col] = vv;
      }
}

// ---------------- chunked EMA scan (packed qvg layout, ld = 3072) ----------------
__global__ __launch_bounds__(256) void scan_local(u16* __restrict__ v,
                                                  float* __restrict__ carry,
                                                  const float* __restrict__ lam,
                                                  int S, int nch, int ld) {
  int bj = blockIdx.x;
  int b = bj / nch, j = bj - b * nch;
  int col0 = threadIdx.x * 4;
  float l = lam[col0 >> 6];
  float s0 = 0.f, s1 = 0.f, s2 = 0.f, s3 = 0.f;
  size_t base = ((size_t)b * S + (size_t)j * CHUNK) * ld + col0;
  for (int t = 0; t < CHUNK; ++t) {
    ushort4* p = (ushort4*)(v + base + (size_t)t * ld);
    ushort4 u = *p;
    s0 = l * s0 + b2f(u.x);
    s1 = l * s1 + b2f(u.y);
    s2 = l * s2 + b2f(u.z);
    s3 = l * s3 + b2f(u.w);
    u.x = f2b(s0); u.y = f2b(s1); u.z = f2b(s2); u.w = f2b(s3);
    *p = u;
  }
  size_t cb = (size_t)bj * D_MODEL + col0;
  carry[cb] = s0; carry[cb + 1] = s1; carry[cb + 2] = s2; carry[cb + 3] = s3;
}

__global__ void scan_carry(float* __restrict__ carry, const float* __restrict__ lam,
                           int B, int nch) {
  int idx = blockIdx.x * blockDim.x + threadIdx.x;
  if (idx >= B * D_MODEL) return;
  int b = idx >> 10, col = idx & (D_MODEL - 1);
  float l = lam[col >> 6];
  float lC = __powf(l, (float)CHUNK);
  float c = 0.f;
  for (int j = 0; j < nch; ++j) {
    size_t a = ((size_t)(b * nch + j)) * D_MODEL + col;
    c = lC * c + carry[a];
    carry[a] = c;
  }
}

// pass 3 fused with q*state, LayerNorm, SiLU gate. One block per row.
__global__ __launch_bounds__(256) void ew_ln(const u16* __restrict__ qvg,
    const float* __restrict__ carry, const float* __restrict__ lam,
    const float* __restrict__ gamma, const float* __restrict__ lbeta,
    u16* __restrict__ yout, int S, int nch, int ld) {
  int row = blockIdx.x;
  int b = row / S, s = row - b * S;
  int j = s / CHUNK, tl = s - j * CHUNK;
  int tid = threadIdx.x;
  int col0 = tid * 4;
  size_t rb = (size_t)row * ld;

  ushort4 qu = *(const ushort4*)(qvg + rb + col0);
  ushort4 su = *(const ushort4*)(qvg + rb + D_MODEL + col0);
  float st[4] = {b2f(su.x), b2f(su.y), b2f(su.z), b2f(su.w)};
  if (j > 0) {
    float l = lam[col0 >> 6];
    float p = __powf(l, (float)(tl + 1));
    const float4 c4 = *(const float4*)(carry + ((size_t)(b * nch + j - 1)) * D_MODEL + col0);
    st[0] += p * c4.x; st[1] += p * c4.y; st[2] += p * c4.z; st[3] += p * c4.w;
  }
  float q[4] = {b2f(qu.x), b2f(qu.y), b2f(qu.z), b2f(qu.w)};
  float y[4];
  float sum = 0.f, sumsq = 0.f;
  #pragma unroll
  for (int i = 0; i < 4; ++i) {
    y[i] = q[i] * st[i];
    sum += y[i];
    sumsq += y[i] * y[i];
  }
  #pragma unroll
  for (int off = 32; off > 0; off >>= 1) {
    sum += __shfl_down(sum, off);
    sumsq += __shfl_down(sumsq, off);
  }
  __shared__ float red[8];
  int ln = tid & 63, wv = tid >> 6;
  if (ln == 0) { red[wv] = sum; red[4 + wv] = sumsq; }
  __syncthreads();
  sum = red[0] + red[1] + red[2] + red[3];
  sumsq = red[4] + red[5] + red[6] + red[7];
  float mu = sum * (1.f / 1024.f);
  float var = sumsq * (1.f / 1024.f) - mu * mu;
  float rstd = rsqrtf(var + LN_EPS);

  float4 gm = *(const float4*)(gamma + col0);
  float4 bt = *(const float4*)(lbeta + col0);
  ushort4 gu = *(const ushort4*)(qvg + rb + 2 * D_MODEL + col0);
  float gv[4]  = {b2f(gu.x), b2f(gu.y), b2f(gu.z), b2f(gu.w)};
  float gmv[4] = {gm.x, gm.y, gm.z, gm.w};
  float btv[4] = {bt.x, bt.y, bt.z, bt.w};
  u16 ov[4];
  #pragma unroll
  for (int i = 0; i < 4; ++i) {
    float gate = gv[i] / (1.f + __expf(-gv[i]));   // SiLU
    float oo = ((y[i] - mu) * rstd * gmv[i] + btv[i]) * gate;
    ov[i] = f2b(oo);
  }
  ushort4 o; o.x = ov[0]; o.y = ov[1]; o.z = ov[2]; o.w = ov[3];
  *(ushort4*)(yout + (size_t)row * D_MODEL + col0) = o;
}

extern "C" void kernel_launch(void* const* d_in, const int* in_sizes, int n_in,
                              void* d_out, int out_size, void* d_ws, size_t ws_size,
                              hipStream_t stream) {
  const float* x     = (const float*)d_in[0];
  const float* Wq    = (const float*)d_in[1];
  const float* Wv    = (const float*)d_in[2];
  const float* Wo    = (const float*)d_in[3];
  const float* Wg    = (const float*)d_in[4];
  const float* beta  = (const float*)d_in[5];
  const float* gamma = (const float*)d_in[6];
  const float* lbeta = (const float*)d_in[7];
  float* out = (float*)d_out;

  const int BS = in_sizes[0] / D_MODEL;     // 16384
  const int S = S_LEN;                       // 4096
  const int B = BS / S;                      // 4
  const int nch = S / CHUNK;                 // 64
  const size_t nx = (size_t)BS * D_MODEL;
  const size_t nw = (size_t)D_MODEL * D_MODEL;
  const int N3 = 3 * D_MODEL;                // 3072

  char* w = (char*)d_ws;
  u16* xb   = (u16*)w;  w += nx * 2;
  u16* wqvg = (u16*)w;  w += 3 * nw * 2;     // packed [Wq;Wv;Wg] rows
  u16* wob  = (u16*)w;  w += nw * 2;
  u16* qvg  = (u16*)w;  w += (size_t)BS * N3 * 2;   // packed [q|state|g] per row
  u16* yb   = (u16*)w;  w += nx * 2;
  float* carry = (float*)w;  w += (size_t)B * nch * D_MODEL * 4;
  float* lam = (float*)w;

  cvt_f32_bf16<<<2048, 256, 0, stream>>>((const float4*)x,  (ushort4*)xb, (int)(nx / 4));
  cvt_f32_bf16<<<1024, 256, 0, stream>>>((const float4*)Wq, (ushort4*)(wqvg), (int)(nw / 4));
  cvt_f32_bf16<<<1024, 256, 0, stream>>>((const float4*)Wv, (ushort4*)(wqvg + nw), (int)(nw / 4));
  cvt_f32_bf16<<<1024, 256, 0, stream>>>((const float4*)Wg, (ushort4*)(wqvg + 2 * nw), (int)(nw / 4));
  cvt_f32_bf16<<<1024, 256, 0, stream>>>((const float4*)Wo, (ushort4*)wob, (int)(nw / 4));
  lam_kernel<<<1, 64, 0, stream>>>(beta, lam);

  dim3 g1(BS / 256, N3 / 256);      // 64 x 12
  gemm256<u16><<<g1, 512, 0, stream>>>(xb, wqvg, qvg, BS, N3, D_MODEL);

  scan_local<<<B * nch, 256, 0, stream>>>(qvg + D_MODEL, carry, lam, S, nch, N3);
  scan_carry<<<(B * D_MODEL + 255) / 256, 256, 0, stream>>>(carry, lam, B, nch);
  ew_ln<<<BS, 256, 0, stream>>>(qvg, carry, lam, gamma, lbeta, yb, S, nch, N3);

  dim3 g2(BS / 256, D_MODEL / 256); // 64 x 4
  gemm256<float><<<g2, 512, 0, stream>>>(yb, wob, out, BS, D_MODEL, D_MODEL);
}

// Round 4
// 252.482 us; speedup vs baseline: 1.1791x; 1.0267x over previous
//
#include <hip/hip_runtime.h>

#define D_MODEL 1024
#define NHEAD 16
#define LN_EPS 1e-5f
#define CHUNK 64
#define S_LEN 4096

typedef unsigned short u16;
typedef __attribute__((ext_vector_type(8))) short short8;
typedef __attribute__((ext_vector_type(4))) float f32x4;

__device__ __forceinline__ u16 f2b(float f) {
  unsigned u = __builtin_bit_cast(unsigned, f);
  u += 0x7FFFu + ((u >> 16) & 1u);   // RNE
  return (u16)(u >> 16);
}
__device__ __forceinline__ float b2f(u16 s) {
  return __builtin_bit_cast(float, ((unsigned)s) << 16);
}

// ---------------- fp32 -> bf16 bulk convert ----------------
__global__ __launch_bounds__(256) void cvt_f32_bf16(const float4* __restrict__ src,
                                                    ushort4* __restrict__ dst, int n4) {
  int i = blockIdx.x * blockDim.x + threadIdx.x;
  int stride = gridDim.x * blockDim.x;
  for (; i < n4; i += stride) {
    float4 f = src[i];
    ushort4 o;
    o.x = f2b(f.x); o.y = f2b(f.y); o.z = f2b(f.z); o.w = f2b(f.w);
    dst[i] = o;
  }
}

__global__ void lam_kernel(const float* __restrict__ beta, float* __restrict__ lam) {
  int h = threadIdx.x;
  if (h < NHEAD) lam[h] = 1.f / (1.f + __expf(-beta[h]));
}

// ============ 256x256 tile, BK=64, 2-dbuf pipelined GEMM (frag-lead) ============
// Out[M,N] = X[M,K] @ W[N,K]^T (bf16 in, fp32 accum). 512 thr = 8 waves (2Mx4N),
// per-wave output 128x64. LDS: 8 units of 16KB = [dbuf][A/B][half][128x64 u16].
// Swizzle: 16B chunk c within each 128B row stored at c^(row&7) (pre-swizzled
// global source + XOR'd ds_read addr) -> conflict-free (verified: 0 conflicts).
// NEW vs r3: quadrant order Q1(A0B0) Q2(A0B1) Q3(A1B1) Q4(A1B0); every frag
// group ds_read 1-2 phases before its consuming MFMA; NO manual lgkmcnt(0)
// (compiler emits minimal counted waits for visible reg deps -> 4-8 reads in
// flight under every MFMA cluster); only 2 barriers per K-tile:
//   ph2-end: vmcnt(4)+lgkmcnt(0)  (A(t+1) glds landed for all waves; own LDS
//            reads drained before A-units get overwritten by t+2 stages)
//   ph3-end: vmcnt(2)             (B(t+1) glds landed for all waves)
// Stages are UNCONDITIONAL (tile idx clamped) so vmcnt FIFO counts are uniform.

__device__ __forceinline__ void glds16(const u16* g, const u16* l) {
  __builtin_amdgcn_global_load_lds(
      (const __attribute__((address_space(1))) unsigned*)g,
      (__attribute__((address_space(3))) unsigned*)l, 16, 0, 0);
}

#define BAR() asm volatile("s_barrier" ::: "memory")
#define SB0() __builtin_amdgcn_sched_barrier(0)

template <typename OutT>
__global__ __launch_bounds__(512, 2) void gemm256(const u16* __restrict__ X,
                                                  const u16* __restrict__ W,
                                                  OutT* __restrict__ Out,
                                                  int M, int N, int K) {
  __shared__ u16 sm[8][8192];   // unit = d*4 + ab*2 + h ; 16 KB each
  const int tid = threadIdx.x;
  const int lane = tid & 63;
  const int wave = tid >> 6;              // 0..7
  const int ln15 = lane & 15, lh = lane >> 4;
  const int wr = wave >> 2, wc = wave & 3;
  const int bm = blockIdx.x * 256, bn = blockIdx.y * 256;
  const int NT = K >> 6;                  // K-tiles of 64 (>= 3)

  // ---- staging source (pre-swizzled global 16B-chunk within 128B row) ----
  const int srow = tid >> 3;                              // 0..63
  const int scol = ((tid & 7) ^ (srow & 7)) << 3;         // u16 col
  const u16* Asrc = X + (size_t)(bm + srow) * K + scol;
  const u16* Bsrc = W + (size_t)(bn + srow) * K + scol;
  const int ldsw = wave * 512;            // wave's u16 offset inside a unit

#define STAGE(u, h, tile, src)                                          \
  { const u16* _g = (src) + (size_t)((h) * 128) * K + (tile) * 64;      \
    glds16(_g,                  &sm[u][ldsw]);                          \
    glds16(_g + (size_t)64 * K, &sm[u][ldsw + 4096]); }

  // ---- ds_read bases (swizzled) ----
  const char* smb = (const char*)&sm[0][0];
  const char* Ard = smb + wr * 16384 + ln15 * 128;
  const char* Brd = smb + (2 + (wc >> 1)) * 16384 + ((wc & 1) * 64 + ln15) * 128;
  const int swz0 = ((lh ^ (ln15 & 7)) << 4);              // ks=0 chunk
  const int swz1 = (((4 + lh) ^ (ln15 & 7)) << 4);        // ks=1 chunk

#define RD_A(DB, MM, S) (*(const short8*)(Ard + (DB) + (MM) * 2048 + (S)))
#define RD_B(DB, NN, S) (*(const short8*)(Brd + (DB) + (NN) * 2048 + (S)))

  f32x4 acc[8][4];
  f32x4 zero = {0.f, 0.f, 0.f, 0.f};
  #pragma unroll
  for (int m = 0; m < 8; ++m)
    #pragma unroll
    for (int n = 0; n < 4; ++n) acc[m][n] = zero;

  short8 a[8][2], b[4][2];

  // quadrant MFMA cluster: rows M0..M0+3 x cols N0..N0+1, both k-slices
#define MFMA_Q(M0, N0)                                                        \
  SB0();                                                                      \
  __builtin_amdgcn_s_setprio(1);                                              \
  _Pragma("unroll")                                                           \
  for (int m = (M0); m < (M0) + 4; ++m)                                       \
    _Pragma("unroll")                                                         \
    for (int n = (N0); n < (N0) + 2; ++n) {                                   \
      acc[m][n] = __builtin_amdgcn_mfma_f32_16x16x32_bf16(a[m][0], b[n][0], acc[m][n], 0, 0, 0); \
      acc[m][n] = __builtin_amdgcn_mfma_f32_16x16x32_bf16(a[m][1], b[n][1], acc[m][n], 0, 0, 0); \
    }                                                                         \
  __builtin_amdgcn_s_setprio(0);                                              \
  SB0();

  // ---- prologue: stage A(0),B(0),A(1); FIFO=[A0h0,A0h1,B0h0,B0h1,A1h0,A1h1] ----
  STAGE(0, 0, 0, Asrc); STAGE(1, 1, 0, Asrc);
  STAGE(2, 0, 0, Bsrc); STAGE(3, 1, 0, Bsrc);
  STAGE(4, 0, 1, Asrc); STAGE(5, 1, 1, Asrc);
  asm volatile("s_waitcnt vmcnt(4)" ::: "memory");   // tile0 landed; A(1) flying
  BAR();
  // pre-read tile-0 groups normally read during the previous tile
  #pragma unroll
  for (int m = 0; m < 4; ++m) { a[m][0] = RD_A(0, m, swz0); a[m][1] = RD_A(0, m, swz1); }
  #pragma unroll
  for (int n = 0; n < 4; ++n) { b[n][0] = RD_B(0, n, swz0); b[n][1] = RD_B(0, n, swz1); }

  for (int t = 0; t < NT; ++t) {
    const int d = t & 1;
    const int db = d * 65536;            // ds_read byte offset, current dbuf
    const int odb = (d ^ 1) * 65536;     // next tile's dbuf
    const int od = (d ^ 1) * 4;          // other dbuf unit base (B stages)
    const int sd = d * 4;                // same dbuf unit base (A stages)
    const int tB = (t + 1 < NT) ? t + 1 : NT - 1;
    const int tA = (t + 2 < NT) ? t + 2 : NT - 1;

    // ---- ph1: read a45(t) [->Q3,Q4]; stage Bh0(t+1); MFMA Q1 = A0 x B0 ----
    a[4][0] = RD_A(db, 4, swz0); a[4][1] = RD_A(db, 4, swz1);
    a[5][0] = RD_A(db, 5, swz0); a[5][1] = RD_A(db, 5, swz1);
    STAGE(od + 2, 0, tB, Bsrc);
    MFMA_Q(0, 0)

    // ---- ph2: read a67(t) [->Q3,Q4]; stage Bh1(t+1); MFMA Q2 = A0 x B1 ----
    a[6][0] = RD_A(db, 6, swz0); a[6][1] = RD_A(db, 6, swz1);
    a[7][0] = RD_A(db, 7, swz0); a[7][1] = RD_A(db, 7, swz1);
    STAGE(od + 3, 1, tB, Bsrc);
    MFMA_Q(0, 2)
    // A(t+1) glds landed (all waves, after barrier); own LDS reads drained so
    // A-units can be overwritten by the t+2 stages in ph3/ph4.
    asm volatile("s_waitcnt vmcnt(4) lgkmcnt(0)" ::: "memory");
    BAR();

    // ---- ph3: read a03(t+1) [->Q1,Q2 next]; MFMA Q3 = A1 x B1; stage Ah0(t+2) ----
    #pragma unroll
    for (int m = 0; m < 4; ++m) { a[m][0] = RD_A(odb, m, swz0); a[m][1] = RD_A(odb, m, swz1); }
    MFMA_Q(4, 2)
    STAGE(sd + 0, 0, tA, Asrc);
    asm volatile("s_waitcnt vmcnt(2)" ::: "memory");   // B(t+1) landed; Ah0(t+2) flying
    BAR();

    // ---- ph4: read b23(t+1); MFMA Q4 = A1 x B0; read b01(t+1); stage Ah1(t+2) ----
    b[2][0] = RD_B(odb, 2, swz0); b[2][1] = RD_B(odb, 2, swz1);
    b[3][0] = RD_B(odb, 3, swz0); b[3][1] = RD_B(odb, 3, swz1);
    MFMA_Q(4, 0)
    b[0][0] = RD_B(odb, 0, swz0); b[0][1] = RD_B(odb, 0, swz1);
    b[1][0] = RD_B(odb, 1, swz0); b[1][1] = RD_B(odb, 1, swz1);
    STAGE(sd + 1, 1, tA, Asrc);
  }
#undef STAGE
#undef RD_A
#undef RD_B
#undef MFMA_Q

  // ---- epilogue: C write ----
  #pragma unroll
  for (int m = 0; m < 8; ++m)
    #pragma unroll
    for (int n = 0; n < 4; ++n)
      #pragma unroll
      for (int r = 0; r < 4; ++r) {
        int row = bm + wr * 128 + m * 16 + lh * 4 + r;   // C/D: row=(lane>>4)*4+reg
        int col = bn + wc * 64 + n * 16 + ln15;          //      col=lane&15
        float vv = acc[m][n][r];
        if constexpr (sizeof(OutT) == 2) Out[(size_t)row * N + col] = f2b(vv);
        else                             Out[(size_t)row * N + col] = vv;
      }
}

// ---------------- chunked EMA scan (packed qvg layout, ld = 3072) ----------------
__global__ __launch_bounds__(256) void scan_local(u16* __restrict__ v,
                                                  float* __restrict__ carry,
                                                  const float* __restrict__ lam,
                                                  int S, int nch, int ld) {
  int bj = blockIdx.x;
  int b = bj / nch, j = bj - b * nch;
  int col0 = threadIdx.x * 4;
  float l = lam[col0 >> 6];
  float s0 = 0.f, s1 = 0.f, s2 = 0.f, s3 = 0.f;
  size_t base = ((size_t)b * S + (size_t)j * CHUNK) * ld + col0;
  for (int t = 0; t < CHUNK; ++t) {
    ushort4* p = (ushort4*)(v + base + (size_t)t * ld);
    ushort4 u = *p;
    s0 = l * s0 + b2f(u.x);
    s1 = l * s1 + b2f(u.y);
    s2 = l * s2 + b2f(u.z);
    s3 = l * s3 + b2f(u.w);
    u.x = f2b(s0); u.y = f2b(s1); u.z = f2b(s2); u.w = f2b(s3);
    *p = u;
  }
  size_t cb = (size_t)bj * D_MODEL + col0;
  carry[cb] = s0; carry[cb + 1] = s1; carry[cb + 2] = s2; carry[cb + 3] = s3;
}

__global__ void scan_carry(float* __restrict__ carry, const float* __restrict__ lam,
                           int B, int nch) {
  int idx = blockIdx.x * blockDim.x + threadIdx.x;
  if (idx >= B * D_MODEL) return;
  int b = idx >> 10, col = idx & (D_MODEL - 1);
  float l = lam[col >> 6];
  float lC = __powf(l, (float)CHUNK);
  float c = 0.f;
  for (int j = 0; j < nch; ++j) {
    size_t a = ((size_t)(b * nch + j)) * D_MODEL + col;
    c = lC * c + carry[a];
    carry[a] = c;
  }
}

// pass 3 fused with q*state, LayerNorm, SiLU gate. One block per row.
__global__ __launch_bounds__(256) void ew_ln(const u16* __restrict__ qvg,
    const float* __restrict__ carry, const float* __restrict__ lam,
    const float* __restrict__ gamma, const float* __restrict__ lbeta,
    u16* __restrict__ yout, int S, int nch, int ld) {
  int row = blockIdx.x;
  int b = row / S, s = row - b * S;
  int j = s / CHUNK, tl = s - j * CHUNK;
  int tid = threadIdx.x;
  int col0 = tid * 4;
  size_t rb = (size_t)row * ld;

  ushort4 qu = *(const ushort4*)(qvg + rb + col0);
  ushort4 su = *(const ushort4*)(qvg + rb + D_MODEL + col0);
  float st[4] = {b2f(su.x), b2f(su.y), b2f(su.z), b2f(su.w)};
  if (j > 0) {
    float l = lam[col0 >> 6];
    float p = __powf(l, (float)(tl + 1));
    const float4 c4 = *(const float4*)(carry + ((size_t)(b * nch + j - 1)) * D_MODEL + col0);
    st[0] += p * c4.x; st[1] += p * c4.y; st[2] += p * c4.z; st[3] += p * c4.w;
  }
  float q[4] = {b2f(qu.x), b2f(qu.y), b2f(qu.z), b2f(qu.w)};
  float y[4];
  float sum = 0.f, sumsq = 0.f;
  #pragma unroll
  for (int i = 0; i < 4; ++i) {
    y[i] = q[i] * st[i];
    sum += y[i];
    sumsq += y[i] * y[i];
  }
  #pragma unroll
  for (int off = 32; off > 0; off >>= 1) {
    sum += __shfl_down(sum, off);
    sumsq += __shfl_down(sumsq, off);
  }
  __shared__ float red[8];
  int ln = tid & 63, wv = tid >> 6;
  if (ln == 0) { red[wv] = sum; red[4 + wv] = sumsq; }
  __syncthreads();
  sum = red[0] + red[1] + red[2] + red[3];
  sumsq = red[4] + red[5] + red[6] + red[7];
  float mu = sum * (1.f / 1024.f);
  float var = sumsq * (1.f / 1024.f) - mu * mu;
  float rstd = rsqrtf(var + LN_EPS);

  float4 gm = *(const float4*)(gamma + col0);
  float4 bt = *(const float4*)(lbeta + col0);
  ushort4 gu = *(const ushort4*)(qvg + rb + 2 * D_MODEL + col0);
  float gv[4]  = {b2f(gu.x), b2f(gu.y), b2f(gu.z), b2f(gu.w)};
  float gmv[4] = {gm.x, gm.y, gm.z, gm.w};
  float btv[4] = {bt.x, bt.y, bt.z, bt.w};
  u16 ov[4];
  #pragma unroll
  for (int i = 0; i < 4; ++i) {
    float gate = gv[i] / (1.f + __expf(-gv[i]));   // SiLU
    float oo = ((y[i] - mu) * rstd * gmv[i] + btv[i]) * gate;
    ov[i] = f2b(oo);
  }
  ushort4 o; o.x = ov[0]; o.y = ov[1]; o.z = ov[2]; o.w = ov[3];
  *(ushort4*)(yout + (size_t)row * D_MODEL + col0) = o;
}

extern "C" void kernel_launch(void* const* d_in, const int* in_sizes, int n_in,
                              void* d_out, int out_size, void* d_ws, size_t ws_size,
                              hipStream_t stream) {
  const float* x     = (const float*)d_in[0];
  const float* Wq    = (const float*)d_in[1];
  const float* Wv    = (const float*)d_in[2];
  const float* Wo    = (const float*)d_in[3];
  const float* Wg    = (const float*)d_in[4];
  const float* beta  = (const float*)d_in[5];
  const float* gamma = (const float*)d_in[6];
  const float* lbeta = (const float*)d_in[7];
  float* out = (float*)d_out;

  const int BS = in_sizes[0] / D_MODEL;     // 16384
  const int S = S_LEN;                       // 4096
  const int B = BS / S;                      // 4
  const int nch = S / CHUNK;                 // 64
  const size_t nx = (size_t)BS * D_MODEL;
  const size_t nw = (size_t)D_MODEL * D_MODEL;
  const int N3 = 3 * D_MODEL;                // 3072

  char* w = (char*)d_ws;
  u16* xb   = (u16*)w;  w += nx * 2;
  u16* wqvg = (u16*)w;  w += 3 * nw * 2;     // packed [Wq;Wv;Wg] rows
  u16* wob  = (u16*)w;  w += nw * 2;
  u16* qvg  = (u16*)w;  w += (size_t)BS * N3 * 2;   // packed [q|state|g] per row
  u16* yb   = (u16*)w;  w += nx * 2;
  float* carry = (float*)w;  w += (size_t)B * nch * D_MODEL * 4;
  float* lam = (float*)w;

  cvt_f32_bf16<<<2048, 256, 0, stream>>>((const float4*)x,  (ushort4*)xb, (int)(nx / 4));
  cvt_f32_bf16<<<1024, 256, 0, stream>>>((const float4*)Wq, (ushort4*)(wqvg), (int)(nw / 4));
  cvt_f32_bf16<<<1024, 256, 0, stream>>>((const float4*)Wv, (ushort4*)(wqvg + nw), (int)(nw / 4));
  cvt_f32_bf16<<<1024, 256, 0, stream>>>((const float4*)Wg, (ushort4*)(wqvg + 2 * nw), (int)(nw / 4));
  cvt_f32_bf16<<<1024, 256, 0, stream>>>((const float4*)Wo, (ushort4*)wob, (int)(nw / 4));
  lam_kernel<<<1, 64, 0, stream>>>(beta, lam);

  dim3 g1(BS / 256, N3 / 256);      // 64 x 12
  gemm256<u16><<<g1, 512, 0, stream>>>(xb, wqvg, qvg, BS, N3, D_MODEL);

  scan_local<<<B * nch, 256, 0, stream>>>(qvg + D_MODEL, carry, lam, S, nch, N3);
  scan_carry<<<(B * D_MODEL + 255) / 256, 256, 0, stream>>>(carry, lam, B, nch);
  ew_ln<<<BS, 256, 0, stream>>>(qvg, carry, lam, gamma, lbeta, yb, S, nch, N3);

  dim3 g2(BS / 256, D_MODEL / 256); // 64 x 4
  gemm256<float><<<g2, 512, 0, stream>>>(yb, wob, out, BS, D_MODEL, D_MODEL);
}

// Round 5
// 250.188 us; speedup vs baseline: 1.1899x; 1.0092x over previous
//
#include <hip/hip_runtime.h>

#define D_MODEL 1024
#define NHEAD 16
#define LN_EPS 1e-5f
#define CHUNK 64
#define S_LEN 4096

typedef unsigned short u16;
typedef __attribute__((ext_vector_type(8))) short short8;
typedef __attribute__((ext_vector_type(4))) float f32x4;

__device__ __forceinline__ u16 f2b(float f) {
  unsigned u = __builtin_bit_cast(unsigned, f);
  u += 0x7FFFu + ((u >> 16) & 1u);   // RNE
  return (u16)(u >> 16);
}
__device__ __forceinline__ float b2f(u16 s) {
  return __builtin_bit_cast(float, ((unsigned)s) << 16);
}

// ---------------- fused fp32->bf16 convert (x + 4 weights) + lam ----------------
__device__ __forceinline__ ushort4 cvt4(float4 f) {
  ushort4 o; o.x = f2b(f.x); o.y = f2b(f.y); o.z = f2b(f.z); o.w = f2b(f.w);
  return o;
}
__global__ __launch_bounds__(256) void cvt_all(
    const float4* __restrict__ x,  const float4* __restrict__ wq,
    const float4* __restrict__ wv, const float4* __restrict__ wg,
    const float4* __restrict__ wo, ushort4* __restrict__ xb,
    ushort4* __restrict__ wqvg, ushort4* __restrict__ wob,
    const float* __restrict__ beta, float* __restrict__ lam,
    int nx4, int nw4) {
  int i = blockIdx.x * blockDim.x + threadIdx.x;
  int stride = gridDim.x * blockDim.x;
  if (blockIdx.x == 0 && threadIdx.x < NHEAD)
    lam[threadIdx.x] = 1.f / (1.f + __expf(-beta[threadIdx.x]));
  for (int j = i; j < nx4; j += stride) xb[j] = cvt4(x[j]);
  for (int j = i; j < nw4; j += stride) wqvg[j] = cvt4(wq[j]);
  for (int j = i; j < nw4; j += stride) wqvg[nw4 + j] = cvt4(wv[j]);
  for (int j = i; j < nw4; j += stride) wqvg[2 * nw4 + j] = cvt4(wg[j]);
  for (int j = i; j < nw4; j += stride) wob[j] = cvt4(wo[j]);
}

// ============ 256x256 tile, BK=64, 8-phase (m201-style) pipelined GEMM ============
// Out[M,N] = X[M,K] @ W[N,K]^T (bf16 in, fp32 accum). 512 thr = 8 waves (2Mx4N).
// Per PHASE all 8 waves compute ONE 128x128 C-quadrant (per wave 64x32 = 4x2
// frags x 2ks = 16 MFMA). Quadrant order (0,0),(1,0),(1,1),(0,1) -> per-wave
// phase reads 12/8/4/0 ds_read_b128; half-tile first-reads stagger Ah0,Bh0@ph1,
// Ah1@ph2, Bh1@ph3. LDS: 8 units 16KB = [dbuf][A-h0,A-h1,B-h0,B-h1].
// Swizzle: 16B chunk c in each 128B row stored at c^(row&7) (pre-swizzled
// global src, XOR'd ds_read) -> conflict-free (verified 0).
// Stage stream (tile t): ph1 Ah1(t+1), ph2 Bh1(t+1), ph3 Ah0(t+2), ph4 Bh0(t+2).
// ONE vmcnt(4) per tile at ph4-end: all of t+1 landed, 2 halves of t+2 flying.
// Per phase: reads; stage; [lgkmcnt(8) if 12 reads]; BAR; lgkmcnt(0);
// setprio(1); 16 MFMA; setprio(0); BAR.   (WAR edges: each unit's ds_reads are
// drained by that phase's lgkmcnt(0), and >=1 barrier separates them from the
// overwriting stage; waves max 1 barrier apart -> safe.)

__device__ __forceinline__ void glds16(const u16* g, const u16* l) {
  __builtin_amdgcn_global_load_lds(
      (const __attribute__((address_space(1))) unsigned*)g,
      (__attribute__((address_space(3))) unsigned*)l, 16, 0, 0);
}

#define BAR() asm volatile("s_barrier" ::: "memory")
#define SB0() __builtin_amdgcn_sched_barrier(0)

template <typename OutT>
__global__ __launch_bounds__(512, 2) void gemm256(const u16* __restrict__ X,
                                                  const u16* __restrict__ W,
                                                  OutT* __restrict__ Out,
                                                  int M, int N, int K) {
  __shared__ u16 sm[8][8192];   // unit = d*4 + {0:Ah0, 1:Ah1, 2:Bh0, 3:Bh1}
  const int tid = threadIdx.x;
  const int lane = tid & 63;
  const int wave = tid >> 6;              // 0..7
  const int ln15 = lane & 15, lh = lane >> 4;
  const int wr = wave >> 2, wc = wave & 3;
  const int bm = blockIdx.x * 256, bn = blockIdx.y * 256;
  const int NT = K >> 6;                  // K-tiles of 64 (>= 2)

  // ---- staging source (pre-swizzled global 16B-chunk within 128B row) ----
  const int srow = tid >> 3;                              // 0..63
  const int scol = ((tid & 7) ^ (srow & 7)) << 3;         // u16 col
  const u16* Asrc = X + (size_t)(bm + srow) * K + scol;
  const u16* Bsrc = W + (size_t)(bn + srow) * K + scol;
  const int ldsw = wave * 512;            // wave's u16 offset inside a unit

#define STAGE(u, h, tile, src)                                          \
  { const u16* _g = (src) + (size_t)((h) * 128) * K + (tile) * 64;      \
    glds16(_g,                  &sm[u][ldsw]);                          \
    glds16(_g + (size_t)64 * K, &sm[u][ldsw + 4096]); }

  // ---- ds_read bases (swizzled). row_in_unit: A = wr*64+m*16+ln15,
  //      B = wc*32+n*16+ln15;  (row&7) == (ln15&7) for both. ----
  const char* smb = (const char*)&sm[0][0];
  const char* ArdB = smb + (wr * 64 + ln15) * 128;
  const char* BrdB = smb + (wc * 32 + ln15) * 128;
  const int swz0 = ((lh ^ (ln15 & 7)) << 4);              // ks=0 chunk
  const int swz1 = (((4 + lh) ^ (ln15 & 7)) << 4);        // ks=1 chunk

  f32x4 acc[2][2][4][2];   // [mh][nh][m][n]
  f32x4 zero = {0.f, 0.f, 0.f, 0.f};
  #pragma unroll
  for (int mh = 0; mh < 2; ++mh)
    #pragma unroll
    for (int nh = 0; nh < 2; ++nh)
      #pragma unroll
      for (int m = 0; m < 4; ++m)
        #pragma unroll
        for (int n = 0; n < 2; ++n) acc[mh][nh][m][n] = zero;

  short8 a0[4][2], a1[4][2], b0[2][2], b1[2][2];

#define MFMA_Q(MH, NH, AR, BR)                                                \
  SB0();                                                                      \
  __builtin_amdgcn_s_setprio(1);                                              \
  _Pragma("unroll")                                                           \
  for (int m = 0; m < 4; ++m)                                                 \
    _Pragma("unroll")                                                         \
    for (int n = 0; n < 2; ++n) {                                             \
      acc[MH][NH][m][n] = __builtin_amdgcn_mfma_f32_16x16x32_bf16(AR[m][0], BR[n][0], acc[MH][NH][m][n], 0, 0, 0); \
      acc[MH][NH][m][n] = __builtin_amdgcn_mfma_f32_16x16x32_bf16(AR[m][1], BR[n][1], acc[MH][NH][m][n], 0, 0, 0); \
    }                                                                         \
  __builtin_amdgcn_s_setprio(0);                                              \
  SB0();

  // ---- prologue: all of tile 0 + {Ah0,Bh0}(1); vmcnt(4) leaves those 2 flying ----
  STAGE(0, 0, 0, Asrc); STAGE(2, 0, 0, Bsrc);
  STAGE(1, 1, 0, Asrc); STAGE(3, 1, 0, Bsrc);
  STAGE(4, 0, 1, Asrc); STAGE(6, 0, 1, Bsrc);
  asm volatile("s_waitcnt vmcnt(4)" ::: "memory");
  BAR();

  for (int t = 0; t < NT; ++t) {
    const int d = t & 1;
    const int sd = d * 4, od = (d ^ 1) * 4;
    const int tS1 = (t + 1 < NT) ? t + 1 : NT - 1;
    const int tS2 = (t + 2 < NT) ? t + 2 : NT - 1;
    const char* Ah0 = ArdB + (sd + 0) * 16384;
    const char* Ah1 = ArdB + (sd + 1) * 16384;
    const char* Bh0 = BrdB + (sd + 2) * 16384;
    const char* Bh1 = BrdB + (sd + 3) * 16384;

    // ---- ph1: read a0 (Ah0, 8) + b0 (Bh0, 4); stage Ah1(t+1); Q(0,0) ----
    #pragma unroll
    for (int m = 0; m < 4; ++m) {
      a0[m][0] = *(const short8*)(Ah0 + m * 2048 + swz0);
      a0[m][1] = *(const short8*)(Ah0 + m * 2048 + swz1);
    }
    #pragma unroll
    for (int n = 0; n < 2; ++n) {
      b0[n][0] = *(const short8*)(Bh0 + n * 2048 + swz0);
      b0[n][1] = *(const short8*)(Bh0 + n * 2048 + swz1);
    }
    STAGE(od + 1, 1, tS1, Asrc);
    asm volatile("s_waitcnt lgkmcnt(8)" ::: "memory");
    BAR();
    asm volatile("s_waitcnt lgkmcnt(0)" ::: "memory");
    MFMA_Q(0, 0, a0, b0)
    BAR();

    // ---- ph2: read a1 (Ah1, 8); stage Bh1(t+1); Q(1,0) ----
    #pragma unroll
    for (int m = 0; m < 4; ++m) {
      a1[m][0] = *(const short8*)(Ah1 + m * 2048 + swz0);
      a1[m][1] = *(const short8*)(Ah1 + m * 2048 + swz1);
    }
    STAGE(od + 3, 1, tS1, Bsrc);
    BAR();
    asm volatile("s_waitcnt lgkmcnt(0)" ::: "memory");
    MFMA_Q(1, 0, a1, b0)
    BAR();

    // ---- ph3: read b1 (Bh1, 4); stage Ah0(t+2); Q(1,1) ----
    #pragma unroll
    for (int n = 0; n < 2; ++n) {
      b1[n][0] = *(const short8*)(Bh1 + n * 2048 + swz0);
      b1[n][1] = *(const short8*)(Bh1 + n * 2048 + swz1);
    }
    STAGE(sd + 0, 0, tS2, Asrc);
    BAR();
    asm volatile("s_waitcnt lgkmcnt(0)" ::: "memory");
    MFMA_Q(1, 1, a1, b1)
    BAR();

    // ---- ph4: stage Bh0(t+2); Q(0,1); tile-boundary vmcnt(4) ----
    STAGE(sd + 2, 0, tS2, Bsrc);
    BAR();
    MFMA_Q(0, 1, a0, b1)
    asm volatile("s_waitcnt vmcnt(4)" ::: "memory");   // t+1 landed; 2 halves of t+2 flying
    BAR();
  }
#undef STAGE
#undef MFMA_Q

  // ---- epilogue: C write ----
  #pragma unroll
  for (int mh = 0; mh < 2; ++mh)
    #pragma unroll
    for (int nh = 0; nh < 2; ++nh)
      #pragma unroll
      for (int m = 0; m < 4; ++m)
        #pragma unroll
        for (int n = 0; n < 2; ++n)
          #pragma unroll
          for (int r = 0; r < 4; ++r) {
            int row = bm + mh * 128 + wr * 64 + m * 16 + lh * 4 + r;
            int col = bn + nh * 128 + wc * 32 + n * 16 + ln15;
            float vv = acc[mh][nh][m][n][r];
            if constexpr (sizeof(OutT) == 2) Out[(size_t)row * N + col] = f2b(vv);
            else                             Out[(size_t)row * N + col] = vv;
          }
}

// ---------------- chunked EMA scan (packed qvg layout, ld = 3072) ----------------
// 2 blocks per (b,chunk): each handles 512 cols. 128 threads x ushort4.
__global__ __launch_bounds__(128) void scan_local(u16* __restrict__ v,
                                                  float* __restrict__ carry,
                                                  const float* __restrict__ lam,
                                                  int S, int nch, int ld) {
  int bj = blockIdx.x >> 1, half = blockIdx.x & 1;
  int b = bj / nch, j = bj - b * nch;
  int col0 = half * 512 + threadIdx.x * 4;
  float l = lam[col0 >> 6];
  float s0 = 0.f, s1 = 0.f, s2 = 0.f, s3 = 0.f;
  size_t base = ((size_t)b * S + (size_t)j * CHUNK) * ld + col0;
  for (int t = 0; t < CHUNK; ++t) {
    ushort4* p = (ushort4*)(v + base + (size_t)t * ld);
    ushort4 u = *p;
    s0 = l * s0 + b2f(u.x);
    s1 = l * s1 + b2f(u.y);
    s2 = l * s2 + b2f(u.z);
    s3 = l * s3 + b2f(u.w);
    u.x = f2b(s0); u.y = f2b(s1); u.z = f2b(s2); u.w = f2b(s3);
    *p = u;
  }
  size_t cb = (size_t)bj * D_MODEL + col0;
  carry[cb] = s0; carry[cb + 1] = s1; carry[cb + 2] = s2; carry[cb + 3] = s3;
}

__global__ void scan_carry(float* __restrict__ carry, const float* __restrict__ lam,
                           int B, int nch) {
  int idx = blockIdx.x * blockDim.x + threadIdx.x;
  if (idx >= B * D_MODEL) return;
  int b = idx >> 10, col = idx & (D_MODEL - 1);
  float l = lam[col >> 6];
  float lC = __powf(l, (float)CHUNK);
  float c = 0.f;
  for (int j = 0; j < nch; ++j) {
    size_t a = ((size_t)(b * nch + j)) * D_MODEL + col;
    c = lC * c + carry[a];
    carry[a] = c;
  }
}

// pass 3 fused with q*state, LayerNorm, SiLU gate. One block per row.
__global__ __launch_bounds__(256) void ew_ln(const u16* __restrict__ qvg,
    const float* __restrict__ carry, const float* __restrict__ lam,
    const float* __restrict__ gamma, const float* __restrict__ lbeta,
    u16* __restrict__ yout, int S, int nch, int ld) {
  int row = blockIdx.x;
  int b = row / S, s = row - b * S;
  int j = s / CHUNK, tl = s - j * CHUNK;
  int tid = threadIdx.x;
  int col0 = tid * 4;
  size_t rb = (size_t)row * ld;

  ushort4 qu = *(const ushort4*)(qvg + rb + col0);
  ushort4 su = *(const ushort4*)(qvg + rb + D_MODEL + col0);
  float st[4] = {b2f(su.x), b2f(su.y), b2f(su.z), b2f(su.w)};
  if (j > 0) {
    float l = lam[col0 >> 6];
    float p = __powf(l, (float)(tl + 1));
    const float4 c4 = *(const float4*)(carry + ((size_t)(b * nch + j - 1)) * D_MODEL + col0);
    st[0] += p * c4.x; st[1] += p * c4.y; st[2] += p * c4.z; st[3] += p * c4.w;
  }
  float q[4] = {b2f(qu.x), b2f(qu.y), b2f(qu.z), b2f(qu.w)};
  float y[4];
  float sum = 0.f, sumsq = 0.f;
  #pragma unroll
  for (int i = 0; i < 4; ++i) {
    y[i] = q[i] * st[i];
    sum += y[i];
    sumsq += y[i] * y[i];
  }
  #pragma unroll
  for (int off = 32; off > 0; off >>= 1) {
    sum += __shfl_down(sum, off);
    sumsq += __shfl_down(sumsq, off);
  }
  __shared__ float red[8];
  int ln = tid & 63, wv = tid >> 6;
  if (ln == 0) { red[wv] = sum; red[4 + wv] = sumsq; }
  __syncthreads();
  sum = red[0] + red[1] + red[2] + red[3];
  sumsq = red[4] + red[5] + red[6] + red[7];
  float mu = sum * (1.f / 1024.f);
  float var = sumsq * (1.f / 1024.f) - mu * mu;
  float rstd = rsqrtf(var + LN_EPS);

  float4 gm = *(const float4*)(gamma + col0);
  float4 bt = *(const float4*)(lbeta + col0);
  ushort4 gu = *(const ushort4*)(qvg + rb + 2 * D_MODEL + col0);
  float gv[4]  = {b2f(gu.x), b2f(gu.y), b2f(gu.z), b2f(gu.w)};
  float gmv[4] = {gm.x, gm.y, gm.z, gm.w};
  float btv[4] = {bt.x, bt.y, bt.z, bt.w};
  u16 ov[4];
  #pragma unroll
  for (int i = 0; i < 4; ++i) {
    float gate = gv[i] / (1.f + __expf(-gv[i]));   // SiLU
    float oo = ((y[i] - mu) * rstd * gmv[i] + btv[i]) * gate;
    ov[i] = f2b(oo);
  }
  ushort4 o; o.x = ov[0]; o.y = ov[1]; o.z = ov[2]; o.w = ov[3];
  *(ushort4*)(yout + (size_t)row * D_MODEL + col0) = o;
}

extern "C" void kernel_launch(void* const* d_in, const int* in_sizes, int n_in,
                              void* d_out, int out_size, void* d_ws, size_t ws_size,
                              hipStream_t stream) {
  const float* x     = (const float*)d_in[0];
  const float* Wq    = (const float*)d_in[1];
  const float* Wv    = (const float*)d_in[2];
  const float* Wo    = (const float*)d_in[3];
  const float* Wg    = (const float*)d_in[4];
  const float* beta  = (const float*)d_in[5];
  const float* gamma = (const float*)d_in[6];
  const float* lbeta = (const float*)d_in[7];
  float* out = (float*)d_out;

  const int BS = in_sizes[0] / D_MODEL;     // 16384
  const int S = S_LEN;                       // 4096
  const int B = BS / S;                      // 4
  const int nch = S / CHUNK;                 // 64
  const size_t nx = (size_t)BS * D_MODEL;
  const size_t nw = (size_t)D_MODEL * D_MODEL;
  const int N3 = 3 * D_MODEL;                // 3072

  char* w = (char*)d_ws;
  u16* xb   = (u16*)w;  w += nx * 2;
  u16* wqvg = (u16*)w;  w += 3 * nw * 2;     // packed [Wq;Wv;Wg] rows
  u16* wob  = (u16*)w;  w += nw * 2;
  u16* qvg  = (u16*)w;  w += (size_t)BS * N3 * 2;   // packed [q|state|g] per row
  u16* yb   = (u16*)w;  w += nx * 2;
  float* carry = (float*)w;  w += (size_t)B * nch * D_MODEL * 4;
  float* lam = (float*)w;

  cvt_all<<<2048, 256, 0, stream>>>((const float4*)x, (const float4*)Wq,
      (const float4*)Wv, (const float4*)Wg, (const float4*)Wo,
      (ushort4*)xb, (ushort4*)wqvg, (ushort4*)wob, beta, lam,
      (int)(nx / 4), (int)(nw / 4));

  dim3 g1(BS / 256, N3 / 256);      // 64 x 12
  gemm256<u16><<<g1, 512, 0, stream>>>(xb, wqvg, qvg, BS, N3, D_MODEL);

  scan_local<<<B * nch * 2, 128, 0, stream>>>(qvg + D_MODEL, carry, lam, S, nch, N3);
  scan_carry<<<(B * D_MODEL + 255) / 256, 256, 0, stream>>>(carry, lam, B, nch);
  ew_ln<<<BS, 256, 0, stream>>>(qvg, carry, lam, gamma, lbeta, yb, S, nch, N3);

  dim3 g2(BS / 256, D_MODEL / 256); // 64 x 4
  gemm256<float><<<g2, 512, 0, stream>>>(yb, wob, out, BS, D_MODEL, D_MODEL);
}

// Round 6
// 237.850 us; speedup vs baseline: 1.2516x; 1.0519x over previous
//
#include <hip/hip_runtime.h>

#define D_MODEL 1024
#define NHEAD 16
#define LN_EPS 1e-5f
#define CHUNK 32
#define S_LEN 4096

typedef unsigned short u16;
typedef __attribute__((ext_vector_type(8))) short short8;
typedef __attribute__((ext_vector_type(4))) float f32x4;

__device__ __forceinline__ u16 f2b(float f) {
  unsigned u = __builtin_bit_cast(unsigned, f);
  u += 0x7FFFu + ((u >> 16) & 1u);   // RNE
  return (u16)(u >> 16);
}
__device__ __forceinline__ float b2f(u16 s) {
  return __builtin_bit_cast(float, ((unsigned)s) << 16);
}

// ---------------- fused fp32->bf16 convert (x + 4 weights) + lam ----------------
__device__ __forceinline__ ushort4 cvt4(float4 f) {
  ushort4 o; o.x = f2b(f.x); o.y = f2b(f.y); o.z = f2b(f.z); o.w = f2b(f.w);
  return o;
}
__global__ __launch_bounds__(256) void cvt_all(
    const float4* __restrict__ x,  const float4* __restrict__ wq,
    const float4* __restrict__ wv, const float4* __restrict__ wg,
    const float4* __restrict__ wo, ushort4* __restrict__ xb,
    ushort4* __restrict__ wqvg, ushort4* __restrict__ wob,
    const float* __restrict__ beta, float* __restrict__ lam,
    int nx4, int nw4) {
  int i = blockIdx.x * blockDim.x + threadIdx.x;
  int stride = gridDim.x * blockDim.x;
  if (blockIdx.x == 0 && threadIdx.x < NHEAD) {
    float l = 1.f / (1.f + __expf(-beta[threadIdx.x]));
    lam[threadIdx.x] = l;                 // lambda
    lam[NHEAD + threadIdx.x] = __log2f(l); // log2(lambda)
  }
  for (int j = i; j < nx4; j += stride) xb[j] = cvt4(x[j]);
  for (int j = i; j < nw4; j += stride) wqvg[j] = cvt4(wq[j]);
  for (int j = i; j < nw4; j += stride) wqvg[nw4 + j] = cvt4(wv[j]);
  for (int j = i; j < nw4; j += stride) wqvg[2 * nw4 + j] = cvt4(wg[j]);
  for (int j = i; j < nw4; j += stride) wob[j] = cvt4(wo[j]);
}

// ============ 256x256 tile, BK=64, 2-dbuf pipelined GEMM (frag-lead) ============
// Out[M,N] = X[M,K] @ W[N,K]^T (bf16 in, fp32 accum). 512 thr = 8 waves (2Mx4N),
// per-wave output 128x64. LDS: 8 units of 16KB = [dbuf][A/B][half][128x64 u16].
// Swizzle: 16B chunk c within each 128B row stored at c^(row&7) (pre-swizzled
// global source + XOR'd ds_read addr) -> conflict-free (verified: 0 conflicts).
// r3 structure, r6 change: NO lgkmcnt(0) at ph2-end. Proof of safety: every
// ds_read is consumed by an MFMA (compiler inserts the minimal counted wait
// before the consumer) and >=1 barrier separates consumption from the stage
// that overwrites the unit:
//   Ah0(t) reads (a0-3, issued ph3(t-1)) consumed by Q2(ph2) < ph2-end bar <
//     stage Ah0(t+2) @ph3.   Ah1(t) reads (a45@ph1,a67@ph2) consumed by
//     Q3(ph3) < ph3-end bar(cross-wave) / program order(own) < stage Ah1 @ph4.
//   B(t) units: staged-into only on the OTHER dbuf; last reads of B(t-1) from
//     that dbuf completed by Q1(t-1), >=2 barriers before stage @ph1(t).
// glds RAW: vmcnt(4)@ph2-end drains A(t+1) before ph3 reads a03(t+1);
//           vmcnt(2)@ph3-end drains B(t+1) before ph4 reads b23/b01(t+1).
// FIFO/tile = [Ah0,Ah1(t+1) from prev ph3/4; Bh0,Bh1(t+1) from ph1/2] = 8.

__device__ __forceinline__ void glds16(const u16* g, const u16* l) {
  __builtin_amdgcn_global_load_lds(
      (const __attribute__((address_space(1))) unsigned*)g,
      (__attribute__((address_space(3))) unsigned*)l, 16, 0, 0);
}

#define BAR() asm volatile("s_barrier" ::: "memory")
#define SB0() __builtin_amdgcn_sched_barrier(0)

template <typename OutT>
__global__ __launch_bounds__(512, 2) void gemm256(const u16* __restrict__ X,
                                                  const u16* __restrict__ W,
                                                  OutT* __restrict__ Out,
                                                  int M, int N, int K) {
  __shared__ u16 sm[8][8192];   // unit = d*4 + ab*2 + h ; 16 KB each
  const int tid = threadIdx.x;
  const int lane = tid & 63;
  const int wave = tid >> 6;              // 0..7
  const int ln15 = lane & 15, lh = lane >> 4;
  const int wr = wave >> 2, wc = wave & 3;
  const int bm = blockIdx.x * 256, bn = blockIdx.y * 256;
  const int NT = K >> 6;                  // K-tiles of 64 (>= 3)

  // ---- staging source (pre-swizzled global 16B-chunk within 128B row) ----
  const int srow = tid >> 3;                              // 0..63
  const int scol = ((tid & 7) ^ (srow & 7)) << 3;         // u16 col
  const u16* Asrc = X + (size_t)(bm + srow) * K + scol;
  const u16* Bsrc = W + (size_t)(bn + srow) * K + scol;
  const int ldsw = wave * 512;            // wave's u16 offset inside a unit

#define STAGE(u, h, tile, src)                                          \
  { const u16* _g = (src) + (size_t)((h) * 128) * K + (tile) * 64;      \
    glds16(_g,                  &sm[u][ldsw]);                          \
    glds16(_g + (size_t)64 * K, &sm[u][ldsw + 4096]); }

  // ---- ds_read bases (swizzled) ----
  const char* smb = (const char*)&sm[0][0];
  const char* Ard = smb + wr * 16384 + ln15 * 128;
  const char* Brd = smb + (2 + (wc >> 1)) * 16384 + ((wc & 1) * 64 + ln15) * 128;
  const int swz0 = ((lh ^ (ln15 & 7)) << 4);              // ks=0 chunk
  const int swz1 = (((4 + lh) ^ (ln15 & 7)) << 4);        // ks=1 chunk

#define RD_A(DB, MM, S) (*(const short8*)(Ard + (DB) + (MM) * 2048 + (S)))
#define RD_B(DB, NN, S) (*(const short8*)(Brd + (DB) + (NN) * 2048 + (S)))

  f32x4 acc[8][4];
  f32x4 zero = {0.f, 0.f, 0.f, 0.f};
  #pragma unroll
  for (int m = 0; m < 8; ++m)
    #pragma unroll
    for (int n = 0; n < 4; ++n) acc[m][n] = zero;

  short8 a[8][2], b[4][2];

  // quadrant MFMA cluster: rows M0..M0+3 x cols N0..N0+1, both k-slices
#define MFMA_Q(M0, N0)                                                        \
  SB0();                                                                      \
  __builtin_amdgcn_s_setprio(1);                                              \
  _Pragma("unroll")                                                           \
  for (int m = (M0); m < (M0) + 4; ++m)                                       \
    _Pragma("unroll")                                                         \
    for (int n = (N0); n < (N0) + 2; ++n) {                                   \
      acc[m][n] = __builtin_amdgcn_mfma_f32_16x16x32_bf16(a[m][0], b[n][0], acc[m][n], 0, 0, 0); \
      acc[m][n] = __builtin_amdgcn_mfma_f32_16x16x32_bf16(a[m][1], b[n][1], acc[m][n], 0, 0, 0); \
    }                                                                         \
  __builtin_amdgcn_s_setprio(0);                                              \
  SB0();

  // ---- prologue: stage A(0),B(0),A(1); FIFO=[A0h0,A0h1,B0h0,B0h1,A1h0,A1h1] ----
  STAGE(0, 0, 0, Asrc); STAGE(1, 1, 0, Asrc);
  STAGE(2, 0, 0, Bsrc); STAGE(3, 1, 0, Bsrc);
  STAGE(4, 0, 1, Asrc); STAGE(5, 1, 1, Asrc);
  asm volatile("s_waitcnt vmcnt(4)" ::: "memory");   // tile0 landed; A(1) flying
  BAR();
  // pre-read tile-0 groups normally read during the previous tile
  #pragma unroll
  for (int m = 0; m < 4; ++m) { a[m][0] = RD_A(0, m, swz0); a[m][1] = RD_A(0, m, swz1); }
  #pragma unroll
  for (int n = 0; n < 4; ++n) { b[n][0] = RD_B(0, n, swz0); b[n][1] = RD_B(0, n, swz1); }

  for (int t = 0; t < NT; ++t) {
    const int d = t & 1;
    const int db = d * 65536;            // ds_read byte offset, current dbuf
    const int odb = (d ^ 1) * 65536;     // next tile's dbuf
    const int od = (d ^ 1) * 4;          // other dbuf unit base (B stages)
    const int sd = d * 4;                // same dbuf unit base (A stages)
    const int tB = (t + 1 < NT) ? t + 1 : NT - 1;
    const int tA = (t + 2 < NT) ? t + 2 : NT - 1;

    // ---- ph1: read a45(t) [->Q3,Q4]; stage Bh0(t+1); MFMA Q1 = A0 x B0 ----
    a[4][0] = RD_A(db, 4, swz0); a[4][1] = RD_A(db, 4, swz1);
    a[5][0] = RD_A(db, 5, swz0); a[5][1] = RD_A(db, 5, swz1);
    STAGE(od + 2, 0, tB, Bsrc);
    MFMA_Q(0, 0)

    // ---- ph2: read a67(t) [->Q3,Q4]; stage Bh1(t+1); MFMA Q2 = A0 x B1 ----
    a[6][0] = RD_A(db, 6, swz0); a[6][1] = RD_A(db, 6, swz1);
    a[7][0] = RD_A(db, 7, swz0); a[7][1] = RD_A(db, 7, swz1);
    STAGE(od + 3, 1, tB, Bsrc);
    MFMA_Q(0, 2)
    // A(t+1) glds landed for all waves after barrier; a45-67 float on (their
    // consumer waits are in Q3/Q4).  [r6: removed lgkmcnt(0) here]
    asm volatile("s_waitcnt vmcnt(4)" ::: "memory");
    BAR();

    // ---- ph3: read a03(t+1) [->Q1,Q2 next]; MFMA Q3 = A1 x B1; stage Ah0(t+2) ----
    #pragma unroll
    for (int m = 0; m < 4; ++m) { a[m][0] = RD_A(odb, m, swz0); a[m][1] = RD_A(odb, m, swz1); }
    MFMA_Q(4, 2)
    STAGE(sd + 0, 0, tA, Asrc);
    asm volatile("s_waitcnt vmcnt(2)" ::: "memory");   // B(t+1) landed; Ah0(t+2) flying
    BAR();

    // ---- ph4: read b23(t+1); MFMA Q4 = A1 x B0; read b01(t+1); stage Ah1(t+2) ----
    b[2][0] = RD_B(odb, 2, swz0); b[2][1] = RD_B(odb, 2, swz1);
    b[3][0] = RD_B(odb, 3, swz0); b[3][1] = RD_B(odb, 3, swz1);
    MFMA_Q(4, 0)
    b[0][0] = RD_B(odb, 0, swz0); b[0][1] = RD_B(odb, 0, swz1);
    b[1][0] = RD_B(odb, 1, swz0); b[1][1] = RD_B(odb, 1, swz1);
    STAGE(sd + 1, 1, tA, Asrc);
  }
#undef STAGE
#undef RD_A
#undef RD_B
#undef MFMA_Q

  // ---- epilogue: C write ----
  #pragma unroll
  for (int m = 0; m < 8; ++m)
    #pragma unroll
    for (int n = 0; n < 4; ++n)
      #pragma unroll
      for (int r = 0; r < 4; ++r) {
        int row = bm + wr * 128 + m * 16 + lh * 4 + r;   // C/D: row=(lane>>4)*4+reg
        int col = bn + wc * 64 + n * 16 + ln15;          //      col=lane&15
        float vv = acc[m][n][r];
        if constexpr (sizeof(OutT) == 2) Out[(size_t)row * N + col] = f2b(vv);
        else                             Out[(size_t)row * N + col] = vv;
      }
}

// ---------------- chunked EMA scan (packed qvg layout, ld = 3072) ----------------
// CHUNK=32, one block per (b,chunk), 256 thr cover all 1024 cols (4 each).
// B*nch = 512 blocks x 4 waves = 8 waves/CU.
__global__ __launch_bounds__(256) void scan_local(u16* __restrict__ v,
                                                  float* __restrict__ carry,
                                                  const float* __restrict__ lam,
                                                  int S, int nch, int ld) {
  int bj = blockIdx.x;
  int b = bj / nch, j = bj - b * nch;
  int col0 = threadIdx.x * 4;
  float l = lam[col0 >> 6];
  float s0 = 0.f, s1 = 0.f, s2 = 0.f, s3 = 0.f;
  size_t base = ((size_t)b * S + (size_t)j * CHUNK) * ld + col0;
  #pragma unroll 4
  for (int t = 0; t < CHUNK; ++t) {
    ushort4* p = (ushort4*)(v + base + (size_t)t * ld);
    ushort4 u = *p;
    s0 = l * s0 + b2f(u.x);
    s1 = l * s1 + b2f(u.y);
    s2 = l * s2 + b2f(u.z);
    s3 = l * s3 + b2f(u.w);
    u.x = f2b(s0); u.y = f2b(s1); u.z = f2b(s2); u.w = f2b(s3);
    *p = u;
  }
  size_t cb = (size_t)bj * D_MODEL + col0;
  carry[cb] = s0; carry[cb + 1] = s1; carry[cb + 2] = s2; carry[cb + 3] = s3;
}

__global__ void scan_carry(float* __restrict__ carry, const float* __restrict__ lam,
                           int B, int nch) {
  int idx = blockIdx.x * blockDim.x + threadIdx.x;
  if (idx >= B * D_MODEL) return;
  int b = idx >> 10, col = idx & (D_MODEL - 1);
  float lC = exp2f(lam[NHEAD + (col >> 6)] * (float)CHUNK);
  float c = 0.f;
  #pragma unroll 4
  for (int j = 0; j < nch; ++j) {
    size_t a = ((size_t)(b * nch + j)) * D_MODEL + col;
    c = lC * c + carry[a];
    carry[a] = c;
  }
}

// pass 3 fused with q*state, LayerNorm, SiLU gate. One block per row.
__global__ __launch_bounds__(256) void ew_ln(const u16* __restrict__ qvg,
    const float* __restrict__ carry, const float* __restrict__ lam,
    const float* __restrict__ gamma, const float* __restrict__ lbeta,
    u16* __restrict__ yout, int S, int nch, int ld) {
  int row = blockIdx.x;
  int b = row / S, s = row - b * S;
  int j = s / CHUNK, tl = s - j * CHUNK;
  int tid = threadIdx.x;
  int col0 = tid * 4;
  size_t rb = (size_t)row * ld;

  ushort4 qu = *(const ushort4*)(qvg + rb + col0);
  ushort4 su = *(const ushort4*)(qvg + rb + D_MODEL + col0);
  float st[4] = {b2f(su.x), b2f(su.y), b2f(su.z), b2f(su.w)};
  if (j > 0) {
    float p = exp2f(lam[NHEAD + (col0 >> 6)] * (float)(tl + 1));
    const float4 c4 = *(const float4*)(carry + ((size_t)(b * nch + j - 1)) * D_MODEL + col0);
    st[0] += p * c4.x; st[1] += p * c4.y; st[2] += p * c4.z; st[3] += p * c4.w;
  }
  float q[4] = {b2f(qu.x), b2f(qu.y), b2f(qu.z), b2f(qu.w)};
  float y[4];
  float sum = 0.f, sumsq = 0.f;
  #pragma unroll
  for (int i = 0; i < 4; ++i) {
    y[i] = q[i] * st[i];
    sum += y[i];
    sumsq += y[i] * y[i];
  }
  #pragma unroll
  for (int off = 32; off > 0; off >>= 1) {
    sum += __shfl_down(sum, off);
    sumsq += __shfl_down(sumsq, off);
  }
  __shared__ float red[8];
  int ln = tid & 63, wv = tid >> 6;
  if (ln == 0) { red[wv] = sum; red[4 + wv] = sumsq; }
  __syncthreads();
  sum = red[0] + red[1] + red[2] + red[3];
  sumsq = red[4] + red[5] + red[6] + red[7];
  float mu = sum * (1.f / 1024.f);
  float var = sumsq * (1.f / 1024.f) - mu * mu;
  float rstd = rsqrtf(var + LN_EPS);

  float4 gm = *(const float4*)(gamma + col0);
  float4 bt = *(const float4*)(lbeta + col0);
  ushort4 gu = *(const ushort4*)(qvg + rb + 2 * D_MODEL + col0);
  float gv[4]  = {b2f(gu.x), b2f(gu.y), b2f(gu.z), b2f(gu.w)};
  float gmv[4] = {gm.x, gm.y, gm.z, gm.w};
  float btv[4] = {bt.x, bt.y, bt.z, bt.w};
  u16 ov[4];
  #pragma unroll
  for (int i = 0; i < 4; ++i) {
    float gate = gv[i] / (1.f + __expf(-gv[i]));   // SiLU
    float oo = ((y[i] - mu) * rstd * gmv[i] + btv[i]) * gate;
    ov[i] = f2b(oo);
  }
  ushort4 o; o.x = ov[0]; o.y = ov[1]; o.z = ov[2]; o.w = ov[3];
  *(ushort4*)(yout + (size_t)row * D_MODEL + col0) = o;
}

extern "C" void kernel_launch(void* const* d_in, const int* in_sizes, int n_in,
                              void* d_out, int out_size, void* d_ws, size_t ws_size,
                              hipStream_t stream) {
  const float* x     = (const float*)d_in[0];
  const float* Wq    = (const float*)d_in[1];
  const float* Wv    = (const float*)d_in[2];
  const float* Wo    = (const float*)d_in[3];
  const float* Wg    = (const float*)d_in[4];
  const float* beta  = (const float*)d_in[5];
  const float* gamma = (const float*)d_in[6];
  const float* lbeta = (const float*)d_in[7];
  float* out = (float*)d_out;

  const int BS = in_sizes[0] / D_MODEL;     // 16384
  const int S = S_LEN;                       // 4096
  const int B = BS / S;                      // 4
  const int nch = S / CHUNK;                 // 128
  const size_t nx = (size_t)BS * D_MODEL;
  const size_t nw = (size_t)D_MODEL * D_MODEL;
  const int N3 = 3 * D_MODEL;                // 3072

  char* w = (char*)d_ws;
  u16* xb   = (u16*)w;  w += nx * 2;
  u16* wqvg = (u16*)w;  w += 3 * nw * 2;     // packed [Wq;Wv;Wg] rows
  u16* wob  = (u16*)w;  w += nw * 2;
  u16* qvg  = (u16*)w;  w += (size_t)BS * N3 * 2;   // packed [q|state|g] per row
  u16* yb   = (u16*)w;  w += nx * 2;
  float* carry = (float*)w;  w += (size_t)B * nch * D_MODEL * 4;
  float* lam = (float*)w;

  cvt_all<<<2048, 256, 0, stream>>>((const float4*)x, (const float4*)Wq,
      (const float4*)Wv, (const float4*)Wg, (const float4*)Wo,
      (ushort4*)xb, (ushort4*)wqvg, (ushort4*)wob, beta, lam,
      (int)(nx / 4), (int)(nw / 4));

  dim3 g1(BS / 256, N3 / 256);      // 64 x 12
  gemm256<u16><<<g1, 512, 0, stream>>>(xb, wqvg, qvg, BS, N3, D_MODEL);

  scan_local<<<B * nch, 256, 0, stream>>>(qvg + D_MODEL, carry, lam, S, nch, N3);
  scan_carry<<<(B * D_MODEL + 255) / 256, 256, 0, stream>>>(carry, lam, B, nch);
  ew_ln<<<BS, 256, 0, stream>>>(qvg, carry, lam, gamma, lbeta, yb, S, nch, N3);

  dim3 g2(BS / 256, D_MODEL / 256); // 64 x 4
  gemm256<float><<<g2, 512, 0, stream>>>(yb, wob, out, BS, D_MODEL, D_MODEL);
}

// Round 7
// 224.687 us; speedup vs baseline: 1.3250x; 1.0586x over previous
//
#include <hip/hip_runtime.h>

#define D_MODEL 1024
#define NHEAD 16
#define LN_EPS 1e-5f
#define CHUNK 32
#define S_LEN 4096
#define NCH (S_LEN / CHUNK)   // 128

typedef unsigned short u16;
typedef __attribute__((ext_vector_type(8))) short short8;
typedef __attribute__((ext_vector_type(4))) float f32x4;

__device__ __forceinline__ u16 f2b(float f) {
  unsigned u = __builtin_bit_cast(unsigned, f);
  u += 0x7FFFu + ((u >> 16) & 1u);   // RNE
  return (u16)(u >> 16);
}
__device__ __forceinline__ float b2f(u16 s) {
  return __builtin_bit_cast(float, ((unsigned)s) << 16);
}

// ---------------- fused fp32->bf16 convert (x + 4 weights) + lam ----------------
__device__ __forceinline__ ushort4 cvt4(float4 f) {
  ushort4 o; o.x = f2b(f.x); o.y = f2b(f.y); o.z = f2b(f.z); o.w = f2b(f.w);
  return o;
}
__global__ __launch_bounds__(256) void cvt_all(
    const float4* __restrict__ x,  const float4* __restrict__ wq,
    const float4* __restrict__ wv, const float4* __restrict__ wg,
    const float4* __restrict__ wo, ushort4* __restrict__ xb,
    ushort4* __restrict__ wqvg, ushort4* __restrict__ wob,
    const float* __restrict__ beta, float* __restrict__ lam,
    int nx4, int nw4) {
  int i = blockIdx.x * blockDim.x + threadIdx.x;
  int stride = gridDim.x * blockDim.x;
  if (blockIdx.x == 0 && threadIdx.x < NHEAD) {
    float l = 1.f / (1.f + __expf(-beta[threadIdx.x]));
    lam[threadIdx.x] = l;                  // lambda
    lam[NHEAD + threadIdx.x] = __log2f(l); // log2(lambda)
  }
  for (int j = i; j < nx4; j += stride) xb[j] = cvt4(x[j]);
  for (int j = i; j < nw4; j += stride) wqvg[j] = cvt4(wq[j]);
  for (int j = i; j < nw4; j += stride) wqvg[nw4 + j] = cvt4(wv[j]);
  for (int j = i; j < nw4; j += stride) wqvg[2 * nw4 + j] = cvt4(wg[j]);
  for (int j = i; j < nw4; j += stride) wob[j] = cvt4(wo[j]);
}

// ============ 256x256 tile, BK=64, 2-dbuf pipelined GEMM (frag-lead, r6) ============
// + CARRY epilogue: for v-column blocks (bn in [1024,2048)), emit per-32-row-chunk
// EMA totals  carry[b*NCH+chunk][col] = sum_u lambda^{31-u} v_u  straight from the
// fp32 accumulators (rows of a chunk live in lh (lane>>4) x m-frag pairs -> weighted
// sum + shfl_down(16)+shfl_down(32); lanes lh==0 store).

__device__ __forceinline__ void glds16(const u16* g, const u16* l) {
  __builtin_amdgcn_global_load_lds(
      (const __attribute__((address_space(1))) unsigned*)g,
      (__attribute__((address_space(3))) unsigned*)l, 16, 0, 0);
}

#define BAR() asm volatile("s_barrier" ::: "memory")
#define SB0() __builtin_amdgcn_sched_barrier(0)

template <typename OutT, bool CARRY>
__global__ __launch_bounds__(512, 2) void gemm256(const u16* __restrict__ X,
                                                  const u16* __restrict__ W,
                                                  OutT* __restrict__ Out,
                                                  float* __restrict__ carry,
                                                  const float* __restrict__ lamlog,
                                                  int M, int N, int K) {
  __shared__ u16 sm[8][8192];   // unit = d*4 + ab*2 + h ; 16 KB each
  const int tid = threadIdx.x;
  const int lane = tid & 63;
  const int wave = tid >> 6;              // 0..7
  const int ln15 = lane & 15, lh = lane >> 4;
  const int wr = wave >> 2, wc = wave & 3;
  const int bm = blockIdx.x * 256, bn = blockIdx.y * 256;
  const int NT = K >> 6;                  // K-tiles of 64 (>= 3)

  // ---- staging source (pre-swizzled global 16B-chunk within 128B row) ----
  const int srow = tid >> 3;                              // 0..63
  const int scol = ((tid & 7) ^ (srow & 7)) << 3;         // u16 col
  const u16* Asrc = X + (size_t)(bm + srow) * K + scol;
  const u16* Bsrc = W + (size_t)(bn + srow) * K + scol;
  const int ldsw = wave * 512;            // wave's u16 offset inside a unit

#define STAGE(u, h, tile, src)                                          \
  { const u16* _g = (src) + (size_t)((h) * 128) * K + (tile) * 64;      \
    glds16(_g,                  &sm[u][ldsw]);                          \
    glds16(_g + (size_t)64 * K, &sm[u][ldsw + 4096]); }

  // ---- ds_read bases (swizzled) ----
  const char* smb = (const char*)&sm[0][0];
  const char* Ard = smb + wr * 16384 + ln15 * 128;
  const char* Brd = smb + (2 + (wc >> 1)) * 16384 + ((wc & 1) * 64 + ln15) * 128;
  const int swz0 = ((lh ^ (ln15 & 7)) << 4);              // ks=0 chunk
  const int swz1 = (((4 + lh) ^ (ln15 & 7)) << 4);        // ks=1 chunk

#define RD_A(DB, MM, S) (*(const short8*)(Ard + (DB) + (MM) * 2048 + (S)))
#define RD_B(DB, NN, S) (*(const short8*)(Brd + (DB) + (NN) * 2048 + (S)))

  f32x4 acc[8][4];
  f32x4 zero = {0.f, 0.f, 0.f, 0.f};
  #pragma unroll
  for (int m = 0; m < 8; ++m)
    #pragma unroll
    for (int n = 0; n < 4; ++n) acc[m][n] = zero;

  short8 a[8][2], b[4][2];

#define MFMA_Q(M0, N0)                                                        \
  SB0();                                                                      \
  __builtin_amdgcn_s_setprio(1);                                              \
  _Pragma("unroll")                                                           \
  for (int m = (M0); m < (M0) + 4; ++m)                                       \
    _Pragma("unroll")                                                         \
    for (int n = (N0); n < (N0) + 2; ++n) {                                   \
      acc[m][n] = __builtin_amdgcn_mfma_f32_16x16x32_bf16(a[m][0], b[n][0], acc[m][n], 0, 0, 0); \
      acc[m][n] = __builtin_amdgcn_mfma_f32_16x16x32_bf16(a[m][1], b[n][1], acc[m][n], 0, 0, 0); \
    }                                                                         \
  __builtin_amdgcn_s_setprio(0);                                              \
  SB0();

  // ---- prologue ----
  STAGE(0, 0, 0, Asrc); STAGE(1, 1, 0, Asrc);
  STAGE(2, 0, 0, Bsrc); STAGE(3, 1, 0, Bsrc);
  STAGE(4, 0, 1, Asrc); STAGE(5, 1, 1, Asrc);
  asm volatile("s_waitcnt vmcnt(4)" ::: "memory");   // tile0 landed; A(1) flying
  BAR();
  #pragma unroll
  for (int m = 0; m < 4; ++m) { a[m][0] = RD_A(0, m, swz0); a[m][1] = RD_A(0, m, swz1); }
  #pragma unroll
  for (int n = 0; n < 4; ++n) { b[n][0] = RD_B(0, n, swz0); b[n][1] = RD_B(0, n, swz1); }

  for (int t = 0; t < NT; ++t) {
    const int d = t & 1;
    const int db = d * 65536;
    const int odb = (d ^ 1) * 65536;
    const int od = (d ^ 1) * 4;
    const int sd = d * 4;
    const int tB = (t + 1 < NT) ? t + 1 : NT - 1;
    const int tA = (t + 2 < NT) ? t + 2 : NT - 1;

    // ---- ph1: read a45(t); stage Bh0(t+1); MFMA Q1 = A0 x B0 ----
    a[4][0] = RD_A(db, 4, swz0); a[4][1] = RD_A(db, 4, swz1);
    a[5][0] = RD_A(db, 5, swz0); a[5][1] = RD_A(db, 5, swz1);
    STAGE(od + 2, 0, tB, Bsrc);
    MFMA_Q(0, 0)

    // ---- ph2: read a67(t); stage Bh1(t+1); MFMA Q2 = A0 x B1 ----
    a[6][0] = RD_A(db, 6, swz0); a[6][1] = RD_A(db, 6, swz1);
    a[7][0] = RD_A(db, 7, swz0); a[7][1] = RD_A(db, 7, swz1);
    STAGE(od + 3, 1, tB, Bsrc);
    MFMA_Q(0, 2)
    asm volatile("s_waitcnt vmcnt(4)" ::: "memory");
    BAR();

    // ---- ph3: read a03(t+1); MFMA Q3 = A1 x B1; stage Ah0(t+2) ----
    #pragma unroll
    for (int m = 0; m < 4; ++m) { a[m][0] = RD_A(odb, m, swz0); a[m][1] = RD_A(odb, m, swz1); }
    MFMA_Q(4, 2)
    STAGE(sd + 0, 0, tA, Asrc);
    asm volatile("s_waitcnt vmcnt(2)" ::: "memory");   // B(t+1) landed; Ah0(t+2) flying
    BAR();

    // ---- ph4: read b23(t+1); MFMA Q4 = A1 x B0; read b01(t+1); stage Ah1(t+2) ----
    b[2][0] = RD_B(odb, 2, swz0); b[2][1] = RD_B(odb, 2, swz1);
    b[3][0] = RD_B(odb, 3, swz0); b[3][1] = RD_B(odb, 3, swz1);
    MFMA_Q(4, 0)
    b[0][0] = RD_B(odb, 0, swz0); b[0][1] = RD_B(odb, 0, swz1);
    b[1][0] = RD_B(odb, 1, swz0); b[1][1] = RD_B(odb, 1, swz1);
    STAGE(sd + 1, 1, tA, Asrc);
  }
#undef STAGE
#undef RD_A
#undef RD_B
#undef MFMA_Q

  // ---- epilogue: C write ----
  #pragma unroll
  for (int m = 0; m < 8; ++m)
    #pragma unroll
    for (int n = 0; n < 4; ++n)
      #pragma unroll
      for (int r = 0; r < 4; ++r) {
        int row = bm + wr * 128 + m * 16 + lh * 4 + r;   // C/D: row=(lane>>4)*4+reg
        int col = bn + wc * 64 + n * 16 + ln15;          //      col=lane&15
        float vv = acc[m][n][r];
        if constexpr (sizeof(OutT) == 2) Out[(size_t)row * N + col] = f2b(vv);
        else                             Out[(size_t)row * N + col] = vv;
      }

  // ---- epilogue 2: per-chunk EMA totals for v-columns ----
  if constexpr (CARRY) {
    if (bn >= 1024 && bn < 2048) {
      const int bidx = bm >> 12;                         // batch (4096 rows each)
      const int chunkbase = ((bm & 4095) >> 5) + wr * 4; // 32-row chunks
      const int colbase = (bn - 1024) + wc * 64;         // v-col base (head-uniform)
      const float l2h = lamlog[colbase >> 6];
      float wgt[2][4];
      #pragma unroll
      for (int mo = 0; mo < 2; ++mo)
        #pragma unroll
        for (int r = 0; r < 4; ++r)
          wgt[mo][r] = exp2f(l2h * (float)(31 - (mo * 16 + lh * 4 + r)));
      #pragma unroll
      for (int mq = 0; mq < 4; ++mq) {      // chunk = chunkbase + mq (rows mq*32..)
        #pragma unroll
        for (int n = 0; n < 4; ++n) {
          float part = 0.f;
          #pragma unroll
          for (int mo = 0; mo < 2; ++mo)
            #pragma unroll
            for (int r = 0; r < 4; ++r)
              part += wgt[mo][r] * acc[mq * 2 + mo][n][r];
          part += __shfl_down(part, 16);
          part += __shfl_down(part, 32);
          if (lh == 0)
            carry[(size_t)(bidx * NCH + chunkbase + mq) * D_MODEL +
                  colbase + n * 16 + ln15] = part;
        }
      }
    }
  }
}

// ---------------- carry prefix: c_j = lambda^CHUNK * c_{j-1} + total_j ----------------
__global__ void scan_carry(float* __restrict__ carry, const float* __restrict__ lam,
                           int B, int nch) {
  int idx = blockIdx.x * blockDim.x + threadIdx.x;
  if (idx >= B * D_MODEL) return;
  int b = idx >> 10, col = idx & (D_MODEL - 1);
  float lC = exp2f(lam[NHEAD + (col >> 6)] * (float)CHUNK);
  float c = 0.f;
  #pragma unroll 4
  for (int j = 0; j < nch; ++j) {
    size_t a = ((size_t)(b * nch + j)) * D_MODEL + col;
    c = lC * c + carry[a];
    carry[a] = c;
  }
}

// ---------------- fused local-scan + q*state + LayerNorm + SiLU gate ----------------
// One block per (b,chunk): walks CHUNK rows sequentially; state kept in regs;
// next-row loads issued before the single per-row __syncthreads (parity LDS slots).
__global__ __launch_bounds__(256) void scan_ln(const u16* __restrict__ qvg,
    const float* __restrict__ carry, const float* __restrict__ lam,
    const float* __restrict__ gamma, const float* __restrict__ lbeta,
    u16* __restrict__ yout, int S, int nch, int ld) {
  const int bj = blockIdx.x;               // b*nch + j
  const int b = bj / nch, j = bj - b * nch;
  const int tid = threadIdx.x;
  const int col0 = tid * 4;
  const float l = lam[col0 >> 6];
  const float4 gm = *(const float4*)(gamma + col0);
  const float4 bt = *(const float4*)(lbeta + col0);

  float cp0 = 0.f, cp1 = 0.f, cp2 = 0.f, cp3 = 0.f;
  if (j > 0) {
    const float4 c4 = *(const float4*)(carry + (size_t)(bj - 1) * D_MODEL + col0);
    cp0 = c4.x; cp1 = c4.y; cp2 = c4.z; cp3 = c4.w;
  }
  float p = l;                              // lambda^{t+1}
  float s0 = 0.f, s1 = 0.f, s2 = 0.f, s3 = 0.f;
  const size_t row0 = (size_t)b * S + (size_t)j * CHUNK;
  const size_t rb0 = row0 * ld;

  ushort4 qu = *(const ushort4*)(qvg + rb0 + col0);
  ushort4 su = *(const ushort4*)(qvg + rb0 + D_MODEL + col0);
  ushort4 gu = *(const ushort4*)(qvg + rb0 + 2 * D_MODEL + col0);

  __shared__ float red[2][8];
  const int ln = tid & 63, wv = tid >> 6;

  for (int t = 0; t < CHUNK; ++t) {
    ushort4 qn, sn, gn;
    if (t + 1 < CHUNK) {                    // prefetch next row (uniform branch)
      size_t nb = rb0 + (size_t)(t + 1) * ld;
      qn = *(const ushort4*)(qvg + nb + col0);
      sn = *(const ushort4*)(qvg + nb + D_MODEL + col0);
      gn = *(const ushort4*)(qvg + nb + 2 * D_MODEL + col0);
    }
    s0 = l * s0 + b2f(su.x);
    s1 = l * s1 + b2f(su.y);
    s2 = l * s2 + b2f(su.z);
    s3 = l * s3 + b2f(su.w);
    float st0 = s0 + p * cp0, st1 = s1 + p * cp1;
    float st2 = s2 + p * cp2, st3 = s3 + p * cp3;
    float y0 = b2f(qu.x) * st0, y1 = b2f(qu.y) * st1;
    float y2 = b2f(qu.z) * st2, y3 = b2f(qu.w) * st3;
    float sum = y0 + y1 + y2 + y3;
    float sumsq = y0 * y0 + y1 * y1 + y2 * y2 + y3 * y3;
    #pragma unroll
    for (int off = 32; off > 0; off >>= 1) {
      sum += __shfl_down(sum, off);
      sumsq += __shfl_down(sumsq, off);
    }
    const int par = t & 1;
    if (ln == 0) { red[par][wv] = sum; red[par][4 + wv] = sumsq; }
    __syncthreads();
    sum = red[par][0] + red[par][1] + red[par][2] + red[par][3];
    sumsq = red[par][4] + red[par][5] + red[par][6] + red[par][7];
    float mu = sum * (1.f / 1024.f);
    float var = sumsq * (1.f / 1024.f) - mu * mu;
    float rstd = rsqrtf(var + LN_EPS);

    float g0 = b2f(gu.x), g1 = b2f(gu.y), g2 = b2f(gu.z), g3 = b2f(gu.w);
    float o0 = ((y0 - mu) * rstd * gm.x + bt.x) * (g0 / (1.f + __expf(-g0)));
    float o1 = ((y1 - mu) * rstd * gm.y + bt.y) * (g1 / (1.f + __expf(-g1)));
    float o2 = ((y2 - mu) * rstd * gm.z + bt.z) * (g2 / (1.f + __expf(-g2)));
    float o3 = ((y3 - mu) * rstd * gm.w + bt.w) * (g3 / (1.f + __expf(-g3)));
    ushort4 o; o.x = f2b(o0); o.y = f2b(o1); o.z = f2b(o2); o.w = f2b(o3);
    *(ushort4*)(yout + (row0 + t) * D_MODEL + col0) = o;

    if (t + 1 < CHUNK) { qu = qn; su = sn; gu = gn; }
    p *= l;
  }
}

extern "C" void kernel_launch(void* const* d_in, const int* in_sizes, int n_in,
                              void* d_out, int out_size, void* d_ws, size_t ws_size,
                              hipStream_t stream) {
  const float* x     = (const float*)d_in[0];
  const float* Wq    = (const float*)d_in[1];
  const float* Wv    = (const float*)d_in[2];
  const float* Wo    = (const float*)d_in[3];
  const float* Wg    = (const float*)d_in[4];
  const float* beta  = (const float*)d_in[5];
  const float* gamma = (const float*)d_in[6];
  const float* lbeta = (const float*)d_in[7];
  float* out = (float*)d_out;

  const int BS = in_sizes[0] / D_MODEL;     // 16384
  const int S = S_LEN;                       // 4096
  const int B = BS / S;                      // 4
  const int nch = NCH;                       // 128
  const size_t nx = (size_t)BS * D_MODEL;
  const size_t nw = (size_t)D_MODEL * D_MODEL;
  const int N3 = 3 * D_MODEL;                // 3072

  char* w = (char*)d_ws;
  u16* xb   = (u16*)w;  w += nx * 2;
  u16* wqvg = (u16*)w;  w += 3 * nw * 2;     // packed [Wq;Wv;Wg] rows
  u16* wob  = (u16*)w;  w += nw * 2;
  u16* qvg  = (u16*)w;  w += (size_t)BS * N3 * 2;   // packed [q|v|g] per row
  u16* yb   = (u16*)w;  w += nx * 2;
  float* carry = (float*)w;  w += (size_t)B * nch * D_MODEL * 4;
  float* lam = (float*)w;

  cvt_all<<<2048, 256, 0, stream>>>((const float4*)x, (const float4*)Wq,
      (const float4*)Wv, (const float4*)Wg, (const float4*)Wo,
      (ushort4*)xb, (ushort4*)wqvg, (ushort4*)wob, beta, lam,
      (int)(nx / 4), (int)(nw / 4));

  dim3 g1(BS / 256, N3 / 256);      // 64 x 12
  gemm256<u16, true><<<g1, 512, 0, stream>>>(xb, wqvg, qvg, carry, lam + NHEAD,
                                             BS, N3, D_MODEL);

  scan_carry<<<(B * D_MODEL + 255) / 256, 256, 0, stream>>>(carry, lam, B, nch);
  scan_ln<<<B * nch, 256, 0, stream>>>(qvg, carry, lam, gamma, lbeta, yb, S, nch, N3);

  dim3 g2(BS / 256, D_MODEL / 256); // 64 x 4
  gemm256<float, false><<<g2, 512, 0, stream>>>(yb, wob, out, nullptr, nullptr,
                                                BS, D_MODEL, D_MODEL);
}